// Round 15
// baseline (199.059 us; speedup 1.0000x reference)
//
#include <hip/hip_runtime.h>
#include <cstddef>
#include <cstdint>

#define NN 20000
#define NE 640000
#define MP 20096       // padded rows (314*64)
#define KA 224         // A row length (halfs)
#define NC 16
#define CHUNK 40000    // NE / NC
#define NB_SCAN 79     // ceil(NN/256)

typedef _Float16 f16x8 __attribute__((ext_vector_type(8)));
typedef float f32x4 __attribute__((ext_vector_type(4)));
typedef unsigned short u16x8 __attribute__((ext_vector_type(8)));

__device__ __forceinline__ float h2f(unsigned short u) {
    _Float16 h;
    *reinterpret_cast<unsigned short*>(&h) = u;
    return (float)h;
}
__device__ __forceinline__ unsigned short f2h(float f) {
    _Float16 h = (_Float16)f;
    return *reinterpret_cast<unsigned short*>(&h);
}
// fp16 two-term split: x ~= hi + lo (22 effective mantissa bits)
__device__ __forceinline__ void splitf(float x, unsigned short& hi, unsigned short& lo) {
    _Float16 h = (_Float16)x;
    _Float16 l = (_Float16)(x - (float)h);
    hi = *reinterpret_cast<unsigned short*>(&h);
    lo = *reinterpret_cast<unsigned short*>(&l);
}

// ---------------- setup ----------------
__global__ void init_kernel(const float* __restrict__ hv0, unsigned short* __restrict__ hf0,
                            int* __restrict__ cnt) {
    int i = blockIdx.x * blockDim.x + threadIdx.x;
    if (i < NC * NN) cnt[i] = 0;
    if (i < NN * 64) hf0[i] = f2h(hv0[i]);
}

__global__ void hist_kernel(const int* __restrict__ dst, int* __restrict__ cnt) {
    int i = blockIdx.x * blockDim.x + threadIdx.x;
    if (i < NE) atomicAdd(&cnt[(i / CHUNK) * NN + dst[i]], 1);
}

__global__ __launch_bounds__(256) void scan1_kernel(const int* __restrict__ cnt,
                                                    int* __restrict__ lp,
                                                    int* __restrict__ bsum) {
    __shared__ int s[256];
    int t = threadIdx.x;
    int i = blockIdx.x * 256 + t;
    int d = 0;
    if (i < NN)
#pragma unroll
        for (int c = 0; c < NC; ++c) d += cnt[c * NN + i];
    s[t] = d;
    __syncthreads();
    for (int off = 1; off < 256; off <<= 1) {
        int v = (t >= off) ? s[t - off] : 0;
        __syncthreads();
        s[t] += v;
        __syncthreads();
    }
    if (i < NN) lp[i] = s[t] - d;
    if (t == 255) bsum[blockIdx.x] = s[255];
}

__global__ __launch_bounds__(256) void scan3_kernel(const int* __restrict__ cnt,
                                                    const int* __restrict__ lp,
                                                    const int* __restrict__ bsum,
                                                    int* __restrict__ row_ptr,
                                                    int* __restrict__ cursor) {
    __shared__ int sb[128];
    int t = threadIdx.x;
    if (t < 128) sb[t] = (t < NB_SCAN) ? bsum[t] : 0;
    __syncthreads();
    for (int off = 1; off < 128; off <<= 1) {
        int u = (t < 128 && t >= off) ? sb[t - off] : 0;
        __syncthreads();
        if (t < 128) sb[t] += u;
        __syncthreads();
    }
    int boff = (blockIdx.x == 0) ? 0 : sb[blockIdx.x - 1];
    int i = blockIdx.x * 256 + t;
    if (i < NN) {
        int run = boff + lp[i];
        row_ptr[i] = run;
#pragma unroll
        for (int c = 0; c < NC; ++c) {
            cursor[c * NN + i] = run;
            run += cnt[c * NN + i];
        }
    }
    if (i == 0) row_ptr[NN] = NE;
}

__global__ void place_kernel(const int* __restrict__ src, const int* __restrict__ dst,
                             int* __restrict__ cursor, int2* __restrict__ adj) {
    int i = blockIdx.x * blockDim.x + threadIdx.x;
    if (i < NE) {
        int d = dst[i];
        int pos = atomicAdd(&cursor[(i / CHUNK) * NN + d], 1);
        adj[pos] = make_int2(src[i], i);
    }
}

// esum[v] = sum of incoming-edge features (round-invariant); also degf.
__global__ __launch_bounds__(256) void esum_csr_kernel(
        const float* __restrict__ ef, const int* __restrict__ row_ptr,
        const int2* __restrict__ adj, float* __restrict__ esum,
        float* __restrict__ degf) {
    int wid = threadIdx.x >> 6, lane = threadIdx.x & 63;
    int v = blockIdx.x * 4 + wid;
    if (v >= NN) return;
    int rp0 = row_ptr[v], rp1 = row_ptr[v + 1];
    int q = lane >> 2;
    int fo = (lane & 3) << 2;
    float4 a0 = make_float4(0.f, 0.f, 0.f, 0.f), a1 = a0;
    int i = rp0 + q;
    for (; i + 16 < rp1; i += 32) {
        int e0 = adj[i].y, e1 = adj[i + 16].y;
        float4 x0 = *(const float4*)(ef + (size_t)e0 * 16 + fo);
        float4 x1 = *(const float4*)(ef + (size_t)e1 * 16 + fo);
        a0.x += x0.x; a0.y += x0.y; a0.z += x0.z; a0.w += x0.w;
        a1.x += x1.x; a1.y += x1.y; a1.z += x1.z; a1.w += x1.w;
    }
    for (; i < rp1; i += 16) {
        int e = adj[i].y;
        float4 x = *(const float4*)(ef + (size_t)e * 16 + fo);
        a0.x += x.x; a0.y += x.y; a0.z += x.z; a0.w += x.w;
    }
    a0.x += a1.x; a0.y += a1.y; a0.z += a1.z; a0.w += a1.w;
#pragma unroll
    for (int m = 4; m < 64; m <<= 1) {
        a0.x += __shfl_xor(a0.x, m);
        a0.y += __shfl_xor(a0.y, m);
        a0.z += __shfl_xor(a0.z, m);
        a0.w += __shfl_xor(a0.w, m);
    }
    if (lane < 4) *(float4*)(esum + (size_t)v * 16 + fo) = a0;
    if (lane == 0) degf[v] = (float)(rp1 - rp0);
}

// Fold: WcT[t][j][k] = sum_m W_msg[t][k][m] * W_ih[t][j][m]   (j<192, k<144)
//       bvec[t][j]   = sum_m b_msg[t][m]    * W_ih[t][j][m]
__global__ __launch_bounds__(192) void fold_kernel(
        const float* __restrict__ W_msg, const float* __restrict__ b_msg,
        const float* __restrict__ W_ih, float* __restrict__ WcT,
        float* __restrict__ bvec) {
    __shared__ float ldsW[64][193];
    int t = blockIdx.x / 9;
    int k0 = (blockIdx.x % 9) * 16;
    int j = threadIdx.x;
    float acc[16];
#pragma unroll
    for (int kk = 0; kk < 16; ++kk) acc[kk] = 0.f;
    float bacc = 0.f;
    for (int mc = 0; mc < 2; ++mc) {
        for (int i = threadIdx.x; i < 192 * 64; i += 192) {
            int jj = i >> 6, mm = i & 63;
            ldsW[mm][jj] = W_ih[((size_t)t * 192 + jj) * 128 + mc * 64 + mm];
        }
        __syncthreads();
        for (int mm = 0; mm < 64; ++mm) {
            float wl = ldsW[mm][j];
            float bm = b_msg[t * 128 + mc * 64 + mm];
            bacc = fmaf(bm, wl, bacc);
#pragma unroll
            for (int kk = 0; kk < 16; ++kk) {
                float wm = W_msg[((size_t)t * 144 + k0 + kk) * 128 + mc * 64 + mm];
                acc[kk] = fmaf(wm, wl, acc[kk]);
            }
        }
        __syncthreads();
    }
#pragma unroll
    for (int kk = 0; kk < 16; ++kk)
        WcT[((size_t)t * 192 + j) * 144 + k0 + kk] = acc[kk];
    if (k0 == 0) bvec[t * 192 + j] = bacc;
}

// B[t][n][k] (n<256, k<224), zero-padded, biases folded — proven algebra,
// fp16 hi/lo pair. Zero-block map (used by gemm fn-splits):
//   k<64:      rows 128-191 zero
//   64<=k<192: rows 192-255 zero
//   k>=192:    all rows may be nonzero (bias col 209)
__global__ void wbig_kernel(const float* __restrict__ WcT, const float* __restrict__ bvec,
                            const float* __restrict__ b_ih, const float* __restrict__ b_hh,
                            const float* __restrict__ W_hh,
                            unsigned short* __restrict__ Bhi, unsigned short* __restrict__ Blo) {
    int idx = blockIdx.x * 256 + threadIdx.x;
    if (idx >= 2 * 256 * KA) return;
    int t = idx / (256 * KA);
    int rem = idx % (256 * KA);
    int n = rem / KA, k = rem % KA;
    float v = 0.f;
    if (n < 192) {
        if (k < 64) {
            if (n < 128) v = W_hh[(size_t)t * 192 * 64 + n * 64 + k];
        } else if (k < 128) {
            v = WcT[((size_t)t * 192 + n) * 144 + k];
        } else if (k < 192) {
            v = WcT[((size_t)t * 192 + n) * 144 + (k - 128)];
        } else if (k < 208) {
            v = WcT[((size_t)t * 192 + n) * 144 + 128 + (k - 192)];
        } else if (k == 208) {
            v = bvec[t * 192 + n];
        } else if (k == 209) {
            v = (n < 128) ? (b_ih[t * 192 + n] + b_hh[t * 192 + n]) : b_ih[t * 192 + n];
        }
    } else {
        int j = n - 64;   // 128..191
        if (k < 64) v = W_hh[(size_t)t * 192 * 64 + j * 64 + k];
        else if (k == 209) v = b_hh[t * 192 + j];
    }
    unsigned short hi, lo;
    splitf(v, hi, lo);
    Bhi[idx] = hi;
    Blo[idx] = lo;
}

// ---------------- per-round ----------------
// A[v][0:224) = [ h | S | deg*h | esum | deg | 1 | 0pad ]; only dgh gets hi/lo.
// 8 lanes x 16B per edge, 8 edge slots, unroll x4 -> 32 edges in flight/wave.
// Tail (atail) fused: lanes 8-11 write k=192..223 from esum/degf.
__global__ __launch_bounds__(256) void gather_kernel(
        const float* __restrict__ hv, const unsigned short* __restrict__ hf,
        const int* __restrict__ row_ptr, const int2* __restrict__ adj,
        const float* __restrict__ esum, const float* __restrict__ degf,
        unsigned short* __restrict__ Ahi, unsigned short* __restrict__ Alo) {
    int wid = threadIdx.x >> 6, lane = threadIdx.x & 63;
    int v = blockIdx.x * 4 + wid;
    if (v >= NN) return;
    int rp0 = row_ptr[v], rp1 = row_ptr[v + 1];
    int q = lane >> 3;            // 8 edge slots
    int fo = (lane & 7) << 3;     // 8 halfs (16B) per lane
    float a0[8], a1[8], a2[8], a3[8];
#pragma unroll
    for (int j = 0; j < 8; ++j) { a0[j] = 0.f; a1[j] = 0.f; a2[j] = 0.f; a3[j] = 0.f; }
    int i = rp0 + q;
    for (; i + 24 < rp1; i += 32) {
        int s0 = adj[i].x, s1 = adj[i + 8].x, s2 = adj[i + 16].x, s3 = adj[i + 24].x;
        u16x8 x0 = *(const u16x8*)(hf + (size_t)s0 * 64 + fo);
        u16x8 x1 = *(const u16x8*)(hf + (size_t)s1 * 64 + fo);
        u16x8 x2 = *(const u16x8*)(hf + (size_t)s2 * 64 + fo);
        u16x8 x3 = *(const u16x8*)(hf + (size_t)s3 * 64 + fo);
#pragma unroll
        for (int j = 0; j < 8; ++j) {
            a0[j] += h2f(x0[j]); a1[j] += h2f(x1[j]);
            a2[j] += h2f(x2[j]); a3[j] += h2f(x3[j]);
        }
    }
    for (; i < rp1; i += 8) {
        int s = adj[i].x;
        u16x8 x = *(const u16x8*)(hf + (size_t)s * 64 + fo);
#pragma unroll
        for (int j = 0; j < 8; ++j) a0[j] += h2f(x[j]);
    }
#pragma unroll
    for (int j = 0; j < 8; ++j) a0[j] += a1[j] + a2[j] + a3[j];
#pragma unroll
    for (int m = 8; m < 64; m <<= 1)
#pragma unroll
        for (int j = 0; j < 8; ++j) a0[j] += __shfl_xor(a0[j], m);
    if (lane < 8) {
        float dg = (float)(rp1 - rp0);
        float4 hA = *(const float4*)(hv + (size_t)v * 64 + lane * 8);
        float4 hB = *(const float4*)(hv + (size_t)v * 64 + lane * 8 + 4);
        float h8[8] = {hA.x, hA.y, hA.z, hA.w, hB.x, hB.y, hB.z, hB.w};
        u16x8 hh, sh, dh, dl;
#pragma unroll
        for (int j = 0; j < 8; ++j) {
            hh[j] = f2h(h8[j]);
            sh[j] = f2h(a0[j]);
            unsigned short thi, tlo;
            splitf(dg * h8[j], thi, tlo);
            dh[j] = thi; dl[j] = tlo;
        }
        *(u16x8*)(Ahi + (size_t)v * KA + fo) = hh;
        *(u16x8*)(Ahi + (size_t)v * KA + 64 + fo) = sh;
        *(u16x8*)(Ahi + (size_t)v * KA + 128 + fo) = dh;
        *(u16x8*)(Alo + (size_t)v * KA + 128 + fo) = dl;
    } else if (lane < 12) {
        int o = lane - 8;   // 0..3 -> halfs 192+8o .. 199+8o
        u16x8 tv;
#pragma unroll
        for (int j = 0; j < 8; ++j) tv[j] = 0;
        if (o < 2) {
#pragma unroll
            for (int j = 0; j < 8; ++j) tv[j] = f2h(esum[(size_t)v * 16 + o * 8 + j]);
        } else if (o == 2) {
            tv[0] = f2h(degf[v]);
            tv[1] = f2h(1.f);
        }
        *(u16x8*)(Ahi + (size_t)v * KA + 192 + o * 8) = tv;
    }
}

// Fused MFMA GEMM (64x256 tile, 256 thr, grid 314) + in-register GRU gates.
// Selective precision (R14, frozen) + zero-block fn skips (per wbig map):
//   phases 0-1 (h):    1 MFMA, fn in {0..7, 12..15}   (rows 128-191 zero)
//   phases 2-3 (S):    1 MFMA, fn in {0..11}          (rows 192-255 zero)
//   phases 4-5 (dgh):  3 MFMA, fn in {0..11}          (rows 192-255 zero)
//   phase  6  (tail):  2 MFMA, fn in {0..15}
// All splits are compile-time loop bounds — no inner-loop branches (R9/R10).
__global__ __launch_bounds__(256) void gemm_gru(
        const _Float16* __restrict__ Ahi, const _Float16* __restrict__ Alo,
        const _Float16* __restrict__ Bhi, const _Float16* __restrict__ Blo,
        const float* __restrict__ hin,
        float* __restrict__ fout, unsigned short* __restrict__ hfout) {
    __shared__ _Float16 Ash[64][40];    // +8 pad
    __shared__ _Float16 Asl[64][40];
    __shared__ _Float16 Bsh[256][40];
    __shared__ _Float16 Bsl[256][40];
    int tid = threadIdx.x;
    int w = tid >> 6, l = tid & 63;
    int row0 = blockIdx.x * 64;
    f32x4 acc[16];
#pragma unroll
    for (int i = 0; i < 16; ++i) acc[i] = (f32x4){0.f, 0.f, 0.f, 0.f};

    int sAr = tid >> 2, sAc = (tid & 3) * 8;   // A stage indices
    int kg = (l >> 4) * 8;
    int ar = w * 16 + (l & 15);
    int lc = l & 15;

    // ---- phases 0-1: h block — hi only, 1 MFMA, skip fn 8-11 ----
#pragma unroll 1
    for (int ks = 0; ks < 2; ++ks) {
        int k0 = ks * 32;
        *(float4*)&Ash[sAr][sAc] = *(const float4*)(Ahi + (size_t)(row0 + sAr) * KA + k0 + sAc);
        {
            const float4* ph = (const float4*)(Bhi + (size_t)tid * KA + k0);
            float4 h0 = ph[0], h1 = ph[1], h2 = ph[2], h3 = ph[3];
            *(float4*)&Bsh[tid][0] = h0;  *(float4*)&Bsh[tid][8] = h1;
            *(float4*)&Bsh[tid][16] = h2; *(float4*)&Bsh[tid][24] = h3;
        }
        __syncthreads();
        f16x8 ah = *(const f16x8*)&Ash[ar][kg];
#pragma unroll
        for (int fn = 0; fn < 8; ++fn) {
            f16x8 bh = *(const f16x8*)&Bsh[fn * 16 + lc][kg];
            acc[fn] = __builtin_amdgcn_mfma_f32_16x16x32_f16(ah, bh, acc[fn], 0, 0, 0);
        }
#pragma unroll
        for (int fn = 12; fn < 16; ++fn) {
            f16x8 bh = *(const f16x8*)&Bsh[fn * 16 + lc][kg];
            acc[fn] = __builtin_amdgcn_mfma_f32_16x16x32_f16(ah, bh, acc[fn], 0, 0, 0);
        }
        __syncthreads();
    }

    // ---- phases 2-3: S block — hi only, 1 MFMA, fn 0-11 ----
#pragma unroll 1
    for (int ks = 2; ks < 4; ++ks) {
        int k0 = ks * 32;
        *(float4*)&Ash[sAr][sAc] = *(const float4*)(Ahi + (size_t)(row0 + sAr) * KA + k0 + sAc);
        {
            const float4* ph = (const float4*)(Bhi + (size_t)tid * KA + k0);
            float4 h0 = ph[0], h1 = ph[1], h2 = ph[2], h3 = ph[3];
            *(float4*)&Bsh[tid][0] = h0;  *(float4*)&Bsh[tid][8] = h1;
            *(float4*)&Bsh[tid][16] = h2; *(float4*)&Bsh[tid][24] = h3;
        }
        __syncthreads();
        f16x8 ah = *(const f16x8*)&Ash[ar][kg];
#pragma unroll
        for (int fn = 0; fn < 12; ++fn) {
            f16x8 bh = *(const f16x8*)&Bsh[fn * 16 + lc][kg];
            acc[fn] = __builtin_amdgcn_mfma_f32_16x16x32_f16(ah, bh, acc[fn], 0, 0, 0);
        }
        __syncthreads();
    }

    // ---- phases 4-5: dgh block — full hi/lo, 3 MFMA, fn 0-11 ----
#pragma unroll 1
    for (int ks = 4; ks < 6; ++ks) {
        int k0 = ks * 32;
        *(float4*)&Ash[sAr][sAc] = *(const float4*)(Ahi + (size_t)(row0 + sAr) * KA + k0 + sAc);
        *(float4*)&Asl[sAr][sAc] = *(const float4*)(Alo + (size_t)(row0 + sAr) * KA + k0 + sAc);
        {
            const float4* ph = (const float4*)(Bhi + (size_t)tid * KA + k0);
            float4 h0 = ph[0], h1 = ph[1], h2 = ph[2], h3 = ph[3];
            *(float4*)&Bsh[tid][0] = h0;  *(float4*)&Bsh[tid][8] = h1;
            *(float4*)&Bsh[tid][16] = h2; *(float4*)&Bsh[tid][24] = h3;
            const float4* pl = (const float4*)(Blo + (size_t)tid * KA + k0);
            float4 l0 = pl[0], l1 = pl[1], l2 = pl[2], l3 = pl[3];
            *(float4*)&Bsl[tid][0] = l0;  *(float4*)&Bsl[tid][8] = l1;
            *(float4*)&Bsl[tid][16] = l2; *(float4*)&Bsl[tid][24] = l3;
        }
        __syncthreads();
        f16x8 ah = *(const f16x8*)&Ash[ar][kg];
        f16x8 al = *(const f16x8*)&Asl[ar][kg];
#pragma unroll
        for (int fn = 0; fn < 12; ++fn) {
            f16x8 bh = *(const f16x8*)&Bsh[fn * 16 + lc][kg];
            f16x8 bl = *(const f16x8*)&Bsl[fn * 16 + lc][kg];
            acc[fn] = __builtin_amdgcn_mfma_f32_16x16x32_f16(ah, bh, acc[fn], 0, 0, 0);
            acc[fn] = __builtin_amdgcn_mfma_f32_16x16x32_f16(ah, bl, acc[fn], 0, 0, 0);
            acc[fn] = __builtin_amdgcn_mfma_f32_16x16x32_f16(al, bh, acc[fn], 0, 0, 0);
        }
        __syncthreads();
    }

    // ---- phase 6: tail (esum/deg/1/bias) — 2 MFMA, all fn ----
    {
        const int k0 = 192;
        *(float4*)&Ash[sAr][sAc] = *(const float4*)(Ahi + (size_t)(row0 + sAr) * KA + k0 + sAc);
        {
            const float4* ph = (const float4*)(Bhi + (size_t)tid * KA + k0);
            float4 h0 = ph[0], h1 = ph[1], h2 = ph[2], h3 = ph[3];
            *(float4*)&Bsh[tid][0] = h0;  *(float4*)&Bsh[tid][8] = h1;
            *(float4*)&Bsh[tid][16] = h2; *(float4*)&Bsh[tid][24] = h3;
            const float4* pl = (const float4*)(Blo + (size_t)tid * KA + k0);
            float4 l0 = pl[0], l1 = pl[1], l2 = pl[2], l3 = pl[3];
            *(float4*)&Bsl[tid][0] = l0;  *(float4*)&Bsl[tid][8] = l1;
            *(float4*)&Bsl[tid][16] = l2; *(float4*)&Bsl[tid][24] = l3;
        }
        __syncthreads();
        f16x8 ah = *(const f16x8*)&Ash[ar][kg];
#pragma unroll
        for (int fn = 0; fn < 16; ++fn) {
            f16x8 bh = *(const f16x8*)&Bsh[fn * 16 + lc][kg];
            f16x8 bl = *(const f16x8*)&Bsl[fn * 16 + lc][kg];
            acc[fn] = __builtin_amdgcn_mfma_f32_16x16x32_f16(ah, bh, acc[fn], 0, 0, 0);
            acc[fn] = __builtin_amdgcn_mfma_f32_16x16x32_f16(ah, bl, acc[fn], 0, 0, 0);
        }
        __syncthreads();
    }

    // epilogue: lane l, reg q -> row = w*16 + (l>>4)*4 + q; col j = (l&15)+16*fj
    int jb = l & 15;
#pragma unroll
    for (int q = 0; q < 4; ++q) {
        int row = row0 + w * 16 + (l >> 4) * 4 + q;
        if (row >= NN) continue;
#pragma unroll
        for (int fj = 0; fj < 4; ++fj) {
            int j = jb + fj * 16;
            float rr = acc[fj][q];
            float zz = acc[4 + fj][q];
            float in_ = acc[8 + fj][q];
            float hn = acc[12 + fj][q];
            float r = 1.f / (1.f + __expf(-rr));
            float z = 1.f / (1.f + __expf(-zz));
            float n = tanhf(in_ + r * hn);
            float h = hin[(size_t)row * 64 + j];
            float val = (1.f - z) * n + z * h;
            fout[(size_t)row * 64 + j] = val;
            hfout[(size_t)row * 64 + j] = f2h(val);
        }
    }
}

extern "C" void kernel_launch(void* const* d_in, const int* in_sizes, int n_in,
                              void* d_out, int out_size, void* d_ws, size_t ws_size,
                              hipStream_t stream) {
    const float* hv0   = (const float*)d_in[0];
    const float* ef    = (const float*)d_in[1];
    const int*   src   = (const int*)d_in[2];
    const int*   dst   = (const int*)d_in[3];
    const float* W_msg = (const float*)d_in[4];
    const float* b_msg = (const float*)d_in[5];
    const float* W_ih  = (const float*)d_in[6];
    const float* W_hh  = (const float*)d_in[7];
    const float* b_ih  = (const float*)d_in[8];
    const float* b_hh  = (const float*)d_in[9];
    float* out = (float*)d_out;

    char* ws = (char*)d_ws;
    size_t off = 0;
    auto alloc = [&](size_t bytes) -> char* {
        char* p = ws + off;
        off = (off + bytes + 255) & ~(size_t)255;
        return p;
    };
    int*   cnt      = (int*)alloc((size_t)NC * NN * 4);
    int*   row_ptr  = (int*)alloc((NN + 1) * 4);
    int*   cursor   = (int*)alloc((size_t)NC * NN * 4);
    int2*  adj      = (int2*)alloc((size_t)NE * 8);
    float* esum     = (float*)alloc((size_t)NN * 16 * 4);
    float* degf     = (float*)alloc(NN * 4);
    float* WcT      = (float*)alloc((size_t)2 * 192 * 144 * 4);
    float* bvec     = (float*)alloc(2 * 192 * 4);
    int*   lp       = (int*)alloc(NN * 4);
    int*   bsum     = (int*)alloc(NB_SCAN * 4);
    unsigned short* Ahi = (unsigned short*)alloc((size_t)MP * KA * 2);
    unsigned short* Alo = (unsigned short*)alloc((size_t)MP * KA * 2);
    unsigned short* Bhi = (unsigned short*)alloc((size_t)2 * 256 * KA * 2);
    unsigned short* Blo = (unsigned short*)alloc((size_t)2 * 256 * KA * 2);
    float* hv1      = (float*)alloc((size_t)NN * 64 * 4);
    unsigned short* hf0 = (unsigned short*)alloc((size_t)NN * 64 * 2);
    unsigned short* hf1 = (unsigned short*)alloc((size_t)NN * 64 * 2);

    init_kernel<<<(NN * 64 + 255) / 256, 256, 0, stream>>>(hv0, hf0, cnt);
    hist_kernel<<<(NE + 255) / 256, 256, 0, stream>>>(dst, cnt);
    scan1_kernel<<<NB_SCAN, 256, 0, stream>>>(cnt, lp, bsum);
    scan3_kernel<<<NB_SCAN, 256, 0, stream>>>(cnt, lp, bsum, row_ptr, cursor);
    place_kernel<<<(NE + 255) / 256, 256, 0, stream>>>(src, dst, cursor, adj);
    esum_csr_kernel<<<(NN + 3) / 4, 256, 0, stream>>>(ef, row_ptr, adj, esum, degf);
    fold_kernel<<<18, 192, 0, stream>>>(W_msg, b_msg, W_ih, WcT, bvec);
    wbig_kernel<<<(2 * 256 * KA + 255) / 256, 256, 0, stream>>>(WcT, bvec, b_ih, b_hh,
                                                                W_hh, Bhi, Blo);

    for (int t = 0; t < 2; ++t) {
        const float* hin = (t == 0) ? hv0 : hv1;
        const unsigned short* hfin = (t == 0) ? hf0 : hf1;
        float* hout = (t == 1) ? out : hv1;
        gather_kernel<<<(NN + 3) / 4, 256, 0, stream>>>(hin, hfin, row_ptr, adj,
                                                        esum, degf, Ahi, Alo);
        gemm_gru<<<MP / 64, 256, 0, stream>>>(
            (const _Float16*)Ahi, (const _Float16*)Alo,
            (const _Float16*)(Bhi + (size_t)t * 256 * KA),
            (const _Float16*)(Blo + (size_t)t * 256 * KA),
            hin, hout, hf1);
    }
}

// Round 16
// 196.712 us; speedup vs baseline: 1.0119x; 1.0119x over previous
//
#include <hip/hip_runtime.h>
#include <cstddef>
#include <cstdint>

#define NN 20000
#define NE 640000
#define MP 20096       // padded rows (314*64)
#define KA 224         // A row length (halfs)
#define NC 16
#define CHUNK 40000    // NE / NC
#define NB_SCAN 79     // ceil(NN/256)

typedef _Float16 f16x8 __attribute__((ext_vector_type(8)));
typedef float f32x4 __attribute__((ext_vector_type(4)));
typedef unsigned short u16x8 __attribute__((ext_vector_type(8)));

__device__ __forceinline__ float h2f(unsigned short u) {
    _Float16 h;
    *reinterpret_cast<unsigned short*>(&h) = u;
    return (float)h;
}
__device__ __forceinline__ unsigned short f2h(float f) {
    _Float16 h = (_Float16)f;
    return *reinterpret_cast<unsigned short*>(&h);
}
// fp16 two-term split: x ~= hi + lo (22 effective mantissa bits)
__device__ __forceinline__ void splitf(float x, unsigned short& hi, unsigned short& lo) {
    _Float16 h = (_Float16)x;
    _Float16 l = (_Float16)(x - (float)h);
    hi = *reinterpret_cast<unsigned short*>(&h);
    lo = *reinterpret_cast<unsigned short*>(&l);
}

// ---------------- setup ----------------
__global__ void init_kernel(const float* __restrict__ hv0, unsigned short* __restrict__ hf0,
                            int* __restrict__ cnt) {
    int i = blockIdx.x * blockDim.x + threadIdx.x;
    if (i < NC * NN) cnt[i] = 0;
    if (i < NN * 64) hf0[i] = f2h(hv0[i]);
}

__global__ void hist_kernel(const int* __restrict__ dst, int* __restrict__ cnt) {
    int i = blockIdx.x * blockDim.x + threadIdx.x;
    if (i < NE) atomicAdd(&cnt[(i / CHUNK) * NN + dst[i]], 1);
}

__global__ __launch_bounds__(256) void scan1_kernel(const int* __restrict__ cnt,
                                                    int* __restrict__ lp,
                                                    int* __restrict__ bsum) {
    __shared__ int s[256];
    int t = threadIdx.x;
    int i = blockIdx.x * 256 + t;
    int d = 0;
    if (i < NN)
#pragma unroll
        for (int c = 0; c < NC; ++c) d += cnt[c * NN + i];
    s[t] = d;
    __syncthreads();
    for (int off = 1; off < 256; off <<= 1) {
        int v = (t >= off) ? s[t - off] : 0;
        __syncthreads();
        s[t] += v;
        __syncthreads();
    }
    if (i < NN) lp[i] = s[t] - d;
    if (t == 255) bsum[blockIdx.x] = s[255];
}

__global__ __launch_bounds__(256) void scan3_kernel(const int* __restrict__ cnt,
                                                    const int* __restrict__ lp,
                                                    const int* __restrict__ bsum,
                                                    int* __restrict__ row_ptr,
                                                    int* __restrict__ cursor) {
    __shared__ int sb[128];
    int t = threadIdx.x;
    if (t < 128) sb[t] = (t < NB_SCAN) ? bsum[t] : 0;
    __syncthreads();
    for (int off = 1; off < 128; off <<= 1) {
        int u = (t < 128 && t >= off) ? sb[t - off] : 0;
        __syncthreads();
        if (t < 128) sb[t] += u;
        __syncthreads();
    }
    int boff = (blockIdx.x == 0) ? 0 : sb[blockIdx.x - 1];
    int i = blockIdx.x * 256 + t;
    if (i < NN) {
        int run = boff + lp[i];
        row_ptr[i] = run;
#pragma unroll
        for (int c = 0; c < NC; ++c) {
            cursor[c * NN + i] = run;
            run += cnt[c * NN + i];
        }
    }
    if (i == 0) row_ptr[NN] = NE;
}

__global__ void place_kernel(const int* __restrict__ src, const int* __restrict__ dst,
                             int* __restrict__ cursor, int2* __restrict__ adj) {
    int i = blockIdx.x * blockDim.x + threadIdx.x;
    if (i < NE) {
        int d = dst[i];
        int pos = atomicAdd(&cursor[(i / CHUNK) * NN + d], 1);
        adj[pos] = make_int2(src[i], i);
    }
}

// esum[v] = sum of incoming-edge features (round-invariant); also degf.
__global__ __launch_bounds__(256) void esum_csr_kernel(
        const float* __restrict__ ef, const int* __restrict__ row_ptr,
        const int2* __restrict__ adj, float* __restrict__ esum,
        float* __restrict__ degf) {
    int wid = threadIdx.x >> 6, lane = threadIdx.x & 63;
    int v = blockIdx.x * 4 + wid;
    if (v >= NN) return;
    int rp0 = row_ptr[v], rp1 = row_ptr[v + 1];
    int q = lane >> 2;
    int fo = (lane & 3) << 2;
    float4 a0 = make_float4(0.f, 0.f, 0.f, 0.f), a1 = a0;
    int i = rp0 + q;
    for (; i + 16 < rp1; i += 32) {
        int e0 = adj[i].y, e1 = adj[i + 16].y;
        float4 x0 = *(const float4*)(ef + (size_t)e0 * 16 + fo);
        float4 x1 = *(const float4*)(ef + (size_t)e1 * 16 + fo);
        a0.x += x0.x; a0.y += x0.y; a0.z += x0.z; a0.w += x0.w;
        a1.x += x1.x; a1.y += x1.y; a1.z += x1.z; a1.w += x1.w;
    }
    for (; i < rp1; i += 16) {
        int e = adj[i].y;
        float4 x = *(const float4*)(ef + (size_t)e * 16 + fo);
        a0.x += x.x; a0.y += x.y; a0.z += x.z; a0.w += x.w;
    }
    a0.x += a1.x; a0.y += a1.y; a0.z += a1.z; a0.w += a1.w;
#pragma unroll
    for (int m = 4; m < 64; m <<= 1) {
        a0.x += __shfl_xor(a0.x, m);
        a0.y += __shfl_xor(a0.y, m);
        a0.z += __shfl_xor(a0.z, m);
        a0.w += __shfl_xor(a0.w, m);
    }
    if (lane < 4) *(float4*)(esum + (size_t)v * 16 + fo) = a0;
    if (lane == 0) degf[v] = (float)(rp1 - rp0);
}

// Fold + B-build in ONE kernel (wbig deleted — R15 post-mortem: it was a pure
// relocation dispatch serially dependent on fold).
// Main blocks (0..17): (t, k0-chunk of 16). acc[kk] = WcT value for
// (t, j, k0+kk); write DIRECTLY into B at the mapped column:
//   WcT col kw<64  -> B col 128+kw   (dgh block)
//   WcT col 64..128-> B col kw       (S block)
//   WcT col 128..144-> B col 64+kw   (esum block, 192..207)
//   bacc (chunk 0) -> B col 208
// Aux blocks (18..): W_hh parts, bias col 209, zeros — identical values to the
// old wbig for those regions. Bit-identical B overall.
__global__ __launch_bounds__(192) void fold_kernel(
        const float* __restrict__ W_msg, const float* __restrict__ b_msg,
        const float* __restrict__ W_ih, const float* __restrict__ b_ih,
        const float* __restrict__ b_hh, const float* __restrict__ W_hh,
        unsigned short* __restrict__ Bhi, unsigned short* __restrict__ Blo) {
    if (blockIdx.x >= 18) {
        // aux: regions not covered by main (per t): n<192 & k<64 (12288),
        // n<192 & k in [209,224) (2880), n>=192 all k (14336) -> 29504/t.
        int aidx = (blockIdx.x - 18) * 192 + threadIdx.x;
        if (aidx >= 2 * 29504) return;
        int t = aidx / 29504, r = aidx % 29504;
        int n, k;
        if (r < 12288) { n = r >> 6; k = r & 63; }
        else if (r < 15168) { int q = r - 12288; n = q / 15; k = 209 + q % 15; }
        else { int q = r - 15168; n = 192 + q / 224; k = q % 224; }
        float v = 0.f;
        if (n < 192) {
            if (k < 64) {
                if (n < 128) v = W_hh[(size_t)t * 192 * 64 + n * 64 + k];
            } else if (k == 209) {
                v = (n < 128) ? (b_ih[t * 192 + n] + b_hh[t * 192 + n]) : b_ih[t * 192 + n];
            }
        } else {
            int j = n - 64;   // 128..191
            if (k < 64) v = W_hh[(size_t)t * 192 * 64 + j * 64 + k];
            else if (k == 209) v = b_hh[t * 192 + j];
        }
        unsigned short hi, lo;
        splitf(v, hi, lo);
        size_t o = ((size_t)t * 256 + n) * KA + k;
        Bhi[o] = hi;
        Blo[o] = lo;
        return;
    }
    __shared__ float ldsW[64][193];
    int t = blockIdx.x / 9;
    int k0 = (blockIdx.x % 9) * 16;
    int j = threadIdx.x;
    float acc[16];
#pragma unroll
    for (int kk = 0; kk < 16; ++kk) acc[kk] = 0.f;
    float bacc = 0.f;
    for (int mc = 0; mc < 2; ++mc) {
        for (int i = threadIdx.x; i < 192 * 64; i += 192) {
            int jj = i >> 6, mm = i & 63;
            ldsW[mm][jj] = W_ih[((size_t)t * 192 + jj) * 128 + mc * 64 + mm];
        }
        __syncthreads();
        for (int mm = 0; mm < 64; ++mm) {
            float wl = ldsW[mm][j];
            float bm = b_msg[t * 128 + mc * 64 + mm];
            bacc = fmaf(bm, wl, bacc);
#pragma unroll
            for (int kk = 0; kk < 16; ++kk) {
                float wm = W_msg[((size_t)t * 144 + k0 + kk) * 128 + mc * 64 + mm];
                acc[kk] = fmaf(wm, wl, acc[kk]);
            }
        }
        __syncthreads();
    }
    size_t rowo = ((size_t)t * 256 + j) * KA;
#pragma unroll
    for (int kk = 0; kk < 16; ++kk) {
        int kw = k0 + kk;
        int bcol = (kw < 64) ? (128 + kw) : ((kw < 128) ? kw : (64 + kw));
        unsigned short hi, lo;
        splitf(acc[kk], hi, lo);
        Bhi[rowo + bcol] = hi;
        Blo[rowo + bcol] = lo;
    }
    if (k0 == 0) {
        unsigned short hi, lo;
        splitf(bacc, hi, lo);
        Bhi[rowo + 208] = hi;
        Blo[rowo + 208] = lo;
    }
}

// ---------------- per-round ----------------
// A[v][0:224) = [ h | S | deg*h | esum | deg | 1 | 0pad ]; only dgh gets hi/lo.
// 8 lanes x 16B per edge, 8 edge slots, unroll x4 -> 32 edges in flight/wave.
// Tail fused: lanes 8-11 write k=192..223 from esum/degf.
__global__ __launch_bounds__(256) void gather_kernel(
        const float* __restrict__ hv, const unsigned short* __restrict__ hf,
        const int* __restrict__ row_ptr, const int2* __restrict__ adj,
        const float* __restrict__ esum, const float* __restrict__ degf,
        unsigned short* __restrict__ Ahi, unsigned short* __restrict__ Alo) {
    int wid = threadIdx.x >> 6, lane = threadIdx.x & 63;
    int v = blockIdx.x * 4 + wid;
    if (v >= NN) return;
    int rp0 = row_ptr[v], rp1 = row_ptr[v + 1];
    int q = lane >> 3;            // 8 edge slots
    int fo = (lane & 7) << 3;     // 8 halfs (16B) per lane
    float a0[8], a1[8], a2[8], a3[8];
#pragma unroll
    for (int j = 0; j < 8; ++j) { a0[j] = 0.f; a1[j] = 0.f; a2[j] = 0.f; a3[j] = 0.f; }
    int i = rp0 + q;
    for (; i + 24 < rp1; i += 32) {
        int s0 = adj[i].x, s1 = adj[i + 8].x, s2 = adj[i + 16].x, s3 = adj[i + 24].x;
        u16x8 x0 = *(const u16x8*)(hf + (size_t)s0 * 64 + fo);
        u16x8 x1 = *(const u16x8*)(hf + (size_t)s1 * 64 + fo);
        u16x8 x2 = *(const u16x8*)(hf + (size_t)s2 * 64 + fo);
        u16x8 x3 = *(const u16x8*)(hf + (size_t)s3 * 64 + fo);
#pragma unroll
        for (int j = 0; j < 8; ++j) {
            a0[j] += h2f(x0[j]); a1[j] += h2f(x1[j]);
            a2[j] += h2f(x2[j]); a3[j] += h2f(x3[j]);
        }
    }
    for (; i < rp1; i += 8) {
        int s = adj[i].x;
        u16x8 x = *(const u16x8*)(hf + (size_t)s * 64 + fo);
#pragma unroll
        for (int j = 0; j < 8; ++j) a0[j] += h2f(x[j]);
    }
#pragma unroll
    for (int j = 0; j < 8; ++j) a0[j] += a1[j] + a2[j] + a3[j];
#pragma unroll
    for (int m = 8; m < 64; m <<= 1)
#pragma unroll
        for (int j = 0; j < 8; ++j) a0[j] += __shfl_xor(a0[j], m);
    if (lane < 8) {
        float dg = (float)(rp1 - rp0);
        float4 hA = *(const float4*)(hv + (size_t)v * 64 + lane * 8);
        float4 hB = *(const float4*)(hv + (size_t)v * 64 + lane * 8 + 4);
        float h8[8] = {hA.x, hA.y, hA.z, hA.w, hB.x, hB.y, hB.z, hB.w};
        u16x8 hh, sh, dh, dl;
#pragma unroll
        for (int j = 0; j < 8; ++j) {
            hh[j] = f2h(h8[j]);
            sh[j] = f2h(a0[j]);
            unsigned short thi, tlo;
            splitf(dg * h8[j], thi, tlo);
            dh[j] = thi; dl[j] = tlo;
        }
        *(u16x8*)(Ahi + (size_t)v * KA + fo) = hh;
        *(u16x8*)(Ahi + (size_t)v * KA + 64 + fo) = sh;
        *(u16x8*)(Ahi + (size_t)v * KA + 128 + fo) = dh;
        *(u16x8*)(Alo + (size_t)v * KA + 128 + fo) = dl;
    } else if (lane < 12) {
        int o = lane - 8;   // 0..3 -> halfs 192+8o .. 199+8o
        u16x8 tv;
#pragma unroll
        for (int j = 0; j < 8; ++j) tv[j] = 0;
        if (o < 2) {
#pragma unroll
            for (int j = 0; j < 8; ++j) tv[j] = f2h(esum[(size_t)v * 16 + o * 8 + j]);
        } else if (o == 2) {
            tv[0] = f2h(degf[v]);
            tv[1] = f2h(1.f);
        }
        *(u16x8*)(Ahi + (size_t)v * KA + 192 + o * 8) = tv;
    }
}

// Fused MFMA GEMM (64x256 tile, 256 thr, grid 314) + in-register GRU gates.
// Selective precision (R14, frozen) + zero-block fn skips:
//   phases 0-1 (h):    1 MFMA, fn in {0..7, 12..15}
//   phases 2-3 (S):    1 MFMA, fn in {0..11}
//   phases 4-5 (dgh):  3 MFMA, fn in {0..11}
//   phase  6  (tail):  2 MFMA, fn in {0..15}
__global__ __launch_bounds__(256) void gemm_gru(
        const _Float16* __restrict__ Ahi, const _Float16* __restrict__ Alo,
        const _Float16* __restrict__ Bhi, const _Float16* __restrict__ Blo,
        const float* __restrict__ hin,
        float* __restrict__ fout, unsigned short* __restrict__ hfout) {
    __shared__ _Float16 Ash[64][40];    // +8 pad
    __shared__ _Float16 Asl[64][40];
    __shared__ _Float16 Bsh[256][40];
    __shared__ _Float16 Bsl[256][40];
    int tid = threadIdx.x;
    int w = tid >> 6, l = tid & 63;
    int row0 = blockIdx.x * 64;
    f32x4 acc[16];
#pragma unroll
    for (int i = 0; i < 16; ++i) acc[i] = (f32x4){0.f, 0.f, 0.f, 0.f};

    int sAr = tid >> 2, sAc = (tid & 3) * 8;
    int kg = (l >> 4) * 8;
    int ar = w * 16 + (l & 15);
    int lc = l & 15;

    // ---- phases 0-1: h block — hi only, 1 MFMA, skip fn 8-11 ----
#pragma unroll 1
    for (int ks = 0; ks < 2; ++ks) {
        int k0 = ks * 32;
        *(float4*)&Ash[sAr][sAc] = *(const float4*)(Ahi + (size_t)(row0 + sAr) * KA + k0 + sAc);
        {
            const float4* ph = (const float4*)(Bhi + (size_t)tid * KA + k0);
            float4 h0 = ph[0], h1 = ph[1], h2 = ph[2], h3 = ph[3];
            *(float4*)&Bsh[tid][0] = h0;  *(float4*)&Bsh[tid][8] = h1;
            *(float4*)&Bsh[tid][16] = h2; *(float4*)&Bsh[tid][24] = h3;
        }
        __syncthreads();
        f16x8 ah = *(const f16x8*)&Ash[ar][kg];
#pragma unroll
        for (int fn = 0; fn < 8; ++fn) {
            f16x8 bh = *(const f16x8*)&Bsh[fn * 16 + lc][kg];
            acc[fn] = __builtin_amdgcn_mfma_f32_16x16x32_f16(ah, bh, acc[fn], 0, 0, 0);
        }
#pragma unroll
        for (int fn = 12; fn < 16; ++fn) {
            f16x8 bh = *(const f16x8*)&Bsh[fn * 16 + lc][kg];
            acc[fn] = __builtin_amdgcn_mfma_f32_16x16x32_f16(ah, bh, acc[fn], 0, 0, 0);
        }
        __syncthreads();
    }

    // ---- phases 2-3: S block — hi only, 1 MFMA, fn 0-11 ----
#pragma unroll 1
    for (int ks = 2; ks < 4; ++ks) {
        int k0 = ks * 32;
        *(float4*)&Ash[sAr][sAc] = *(const float4*)(Ahi + (size_t)(row0 + sAr) * KA + k0 + sAc);
        {
            const float4* ph = (const float4*)(Bhi + (size_t)tid * KA + k0);
            float4 h0 = ph[0], h1 = ph[1], h2 = ph[2], h3 = ph[3];
            *(float4*)&Bsh[tid][0] = h0;  *(float4*)&Bsh[tid][8] = h1;
            *(float4*)&Bsh[tid][16] = h2; *(float4*)&Bsh[tid][24] = h3;
        }
        __syncthreads();
        f16x8 ah = *(const f16x8*)&Ash[ar][kg];
#pragma unroll
        for (int fn = 0; fn < 12; ++fn) {
            f16x8 bh = *(const f16x8*)&Bsh[fn * 16 + lc][kg];
            acc[fn] = __builtin_amdgcn_mfma_f32_16x16x32_f16(ah, bh, acc[fn], 0, 0, 0);
        }
        __syncthreads();
    }

    // ---- phases 4-5: dgh block — full hi/lo, 3 MFMA, fn 0-11 ----
#pragma unroll 1
    for (int ks = 4; ks < 6; ++ks) {
        int k0 = ks * 32;
        *(float4*)&Ash[sAr][sAc] = *(const float4*)(Ahi + (size_t)(row0 + sAr) * KA + k0 + sAc);
        *(float4*)&Asl[sAr][sAc] = *(const float4*)(Alo + (size_t)(row0 + sAr) * KA + k0 + sAc);
        {
            const float4* ph = (const float4*)(Bhi + (size_t)tid * KA + k0);
            float4 h0 = ph[0], h1 = ph[1], h2 = ph[2], h3 = ph[3];
            *(float4*)&Bsh[tid][0] = h0;  *(float4*)&Bsh[tid][8] = h1;
            *(float4*)&Bsh[tid][16] = h2; *(float4*)&Bsh[tid][24] = h3;
            const float4* pl = (const float4*)(Blo + (size_t)tid * KA + k0);
            float4 l0 = pl[0], l1 = pl[1], l2 = pl[2], l3 = pl[3];
            *(float4*)&Bsl[tid][0] = l0;  *(float4*)&Bsl[tid][8] = l1;
            *(float4*)&Bsl[tid][16] = l2; *(float4*)&Bsl[tid][24] = l3;
        }
        __syncthreads();
        f16x8 ah = *(const f16x8*)&Ash[ar][kg];
        f16x8 al = *(const f16x8*)&Asl[ar][kg];
#pragma unroll
        for (int fn = 0; fn < 12; ++fn) {
            f16x8 bh = *(const f16x8*)&Bsh[fn * 16 + lc][kg];
            f16x8 bl = *(const f16x8*)&Bsl[fn * 16 + lc][kg];
            acc[fn] = __builtin_amdgcn_mfma_f32_16x16x32_f16(ah, bh, acc[fn], 0, 0, 0);
            acc[fn] = __builtin_amdgcn_mfma_f32_16x16x32_f16(ah, bl, acc[fn], 0, 0, 0);
            acc[fn] = __builtin_amdgcn_mfma_f32_16x16x32_f16(al, bh, acc[fn], 0, 0, 0);
        }
        __syncthreads();
    }

    // ---- phase 6: tail (esum/deg/1/bias) — 2 MFMA, all fn ----
    {
        const int k0 = 192;
        *(float4*)&Ash[sAr][sAc] = *(const float4*)(Ahi + (size_t)(row0 + sAr) * KA + k0 + sAc);
        {
            const float4* ph = (const float4*)(Bhi + (size_t)tid * KA + k0);
            float4 h0 = ph[0], h1 = ph[1], h2 = ph[2], h3 = ph[3];
            *(float4*)&Bsh[tid][0] = h0;  *(float4*)&Bsh[tid][8] = h1;
            *(float4*)&Bsh[tid][16] = h2; *(float4*)&Bsh[tid][24] = h3;
            const float4* pl = (const float4*)(Blo + (size_t)tid * KA + k0);
            float4 l0 = pl[0], l1 = pl[1], l2 = pl[2], l3 = pl[3];
            *(float4*)&Bsl[tid][0] = l0;  *(float4*)&Bsl[tid][8] = l1;
            *(float4*)&Bsl[tid][16] = l2; *(float4*)&Bsl[tid][24] = l3;
        }
        __syncthreads();
        f16x8 ah = *(const f16x8*)&Ash[ar][kg];
#pragma unroll
        for (int fn = 0; fn < 16; ++fn) {
            f16x8 bh = *(const f16x8*)&Bsh[fn * 16 + lc][kg];
            f16x8 bl = *(const f16x8*)&Bsl[fn * 16 + lc][kg];
            acc[fn] = __builtin_amdgcn_mfma_f32_16x16x32_f16(ah, bh, acc[fn], 0, 0, 0);
            acc[fn] = __builtin_amdgcn_mfma_f32_16x16x32_f16(ah, bl, acc[fn], 0, 0, 0);
        }
        __syncthreads();
    }

    // epilogue
    int jb = l & 15;
#pragma unroll
    for (int q = 0; q < 4; ++q) {
        int row = row0 + w * 16 + (l >> 4) * 4 + q;
        if (row >= NN) continue;
#pragma unroll
        for (int fj = 0; fj < 4; ++fj) {
            int j = jb + fj * 16;
            float rr = acc[fj][q];
            float zz = acc[4 + fj][q];
            float in_ = acc[8 + fj][q];
            float hn = acc[12 + fj][q];
            float r = 1.f / (1.f + __expf(-rr));
            float z = 1.f / (1.f + __expf(-zz));
            float n = tanhf(in_ + r * hn);
            float h = hin[(size_t)row * 64 + j];
            float val = (1.f - z) * n + z * h;
            fout[(size_t)row * 64 + j] = val;
            hfout[(size_t)row * 64 + j] = f2h(val);
        }
    }
}

extern "C" void kernel_launch(void* const* d_in, const int* in_sizes, int n_in,
                              void* d_out, int out_size, void* d_ws, size_t ws_size,
                              hipStream_t stream) {
    const float* hv0   = (const float*)d_in[0];
    const float* ef    = (const float*)d_in[1];
    const int*   src   = (const int*)d_in[2];
    const int*   dst   = (const int*)d_in[3];
    const float* W_msg = (const float*)d_in[4];
    const float* b_msg = (const float*)d_in[5];
    const float* W_ih  = (const float*)d_in[6];
    const float* W_hh  = (const float*)d_in[7];
    const float* b_ih  = (const float*)d_in[8];
    const float* b_hh  = (const float*)d_in[9];
    float* out = (float*)d_out;

    char* ws = (char*)d_ws;
    size_t off = 0;
    auto alloc = [&](size_t bytes) -> char* {
        char* p = ws + off;
        off = (off + bytes + 255) & ~(size_t)255;
        return p;
    };
    int*   cnt      = (int*)alloc((size_t)NC * NN * 4);
    int*   row_ptr  = (int*)alloc((NN + 1) * 4);
    int*   cursor   = (int*)alloc((size_t)NC * NN * 4);
    int2*  adj      = (int2*)alloc((size_t)NE * 8);
    float* esum     = (float*)alloc((size_t)NN * 16 * 4);
    float* degf     = (float*)alloc(NN * 4);
    int*   lp       = (int*)alloc(NN * 4);
    int*   bsum     = (int*)alloc(NB_SCAN * 4);
    unsigned short* Ahi = (unsigned short*)alloc((size_t)MP * KA * 2);
    unsigned short* Alo = (unsigned short*)alloc((size_t)MP * KA * 2);
    unsigned short* Bhi = (unsigned short*)alloc((size_t)2 * 256 * KA * 2);
    unsigned short* Blo = (unsigned short*)alloc((size_t)2 * 256 * KA * 2);
    float* hv1      = (float*)alloc((size_t)NN * 64 * 4);
    unsigned short* hf0 = (unsigned short*)alloc((size_t)NN * 64 * 2);
    unsigned short* hf1 = (unsigned short*)alloc((size_t)NN * 64 * 2);

    init_kernel<<<(NN * 64 + 255) / 256, 256, 0, stream>>>(hv0, hf0, cnt);
    hist_kernel<<<(NE + 255) / 256, 256, 0, stream>>>(dst, cnt);
    scan1_kernel<<<NB_SCAN, 256, 0, stream>>>(cnt, lp, bsum);
    scan3_kernel<<<NB_SCAN, 256, 0, stream>>>(cnt, lp, bsum, row_ptr, cursor);
    place_kernel<<<(NE + 255) / 256, 256, 0, stream>>>(src, dst, cursor, adj);
    esum_csr_kernel<<<(NN + 3) / 4, 256, 0, stream>>>(ef, row_ptr, adj, esum, degf);
    // 18 main blocks + 308 aux blocks (2*29504 aux elems / 192)
    fold_kernel<<<18 + (2 * 29504 + 191) / 192, 192, 0, stream>>>(
        W_msg, b_msg, W_ih, b_ih, b_hh, W_hh, Bhi, Blo);

    for (int t = 0; t < 2; ++t) {
        const float* hin = (t == 0) ? hv0 : hv1;
        const unsigned short* hfin = (t == 0) ? hf0 : hf1;
        float* hout = (t == 1) ? out : hv1;
        gather_kernel<<<(NN + 3) / 4, 256, 0, stream>>>(hin, hfin, row_ptr, adj,
                                                        esum, degf, Ahi, Alo);
        gemm_gru<<<MP / 64, 256, 0, stream>>>(
            (const _Float16*)Ahi, (const _Float16*)Alo,
            (const _Float16*)(Bhi + (size_t)t * 256 * KA),
            (const _Float16*)(Blo + (size_t)t * 256 * KA),
            hin, hout, hf1);
    }
}

// Round 17
// 182.157 us; speedup vs baseline: 1.0928x; 1.0799x over previous
//
#include <hip/hip_runtime.h>
#include <cstddef>
#include <cstdint>

#define NN 20000
#define NE 640000
#define MP 20096       // padded rows (314*64)
#define KA 224         // A row length (halfs)
#define NC 16
#define CHUNK 40000    // NE / NC
#define NB_SCAN 79     // ceil(NN/256)

typedef _Float16 f16x8 __attribute__((ext_vector_type(8)));
typedef float f32x4 __attribute__((ext_vector_type(4)));
typedef unsigned short u16x8 __attribute__((ext_vector_type(8)));
typedef unsigned short u16x4 __attribute__((ext_vector_type(4)));

__device__ __forceinline__ float h2f(unsigned short u) {
    _Float16 h;
    *reinterpret_cast<unsigned short*>(&h) = u;
    return (float)h;
}
__device__ __forceinline__ unsigned short f2h(float f) {
    _Float16 h = (_Float16)f;
    return *reinterpret_cast<unsigned short*>(&h);
}
// fp16 two-term split: x ~= hi + lo (22 effective mantissa bits)
__device__ __forceinline__ void splitf(float x, unsigned short& hi, unsigned short& lo) {
    _Float16 h = (_Float16)x;
    _Float16 l = (_Float16)(x - (float)h);
    hi = *reinterpret_cast<unsigned short*>(&h);
    lo = *reinterpret_cast<unsigned short*>(&l);
}

// ---------------- setup ----------------
// ONE prep kernel (R16 post-mortem: chain-shortening is the paying lever):
//   blocks [0,5000):     zero cnt + build fp16 h table
//   blocks [5000,5018):  fold main (t, k0-chunk) -> B direct (mapped cols)
//   blocks [5018,5249):  fold aux  (W_hh regions, bias col 209, zeros)
// B values bit-identical to R16's fold_kernel.
__global__ __launch_bounds__(256) void prep_kernel(
        const float* __restrict__ hv0, unsigned short* __restrict__ hf0,
        int* __restrict__ cnt,
        const float* __restrict__ W_msg, const float* __restrict__ b_msg,
        const float* __restrict__ W_ih, const float* __restrict__ b_ih,
        const float* __restrict__ b_hh, const float* __restrict__ W_hh,
        unsigned short* __restrict__ Bhi, unsigned short* __restrict__ Blo) {
    int b = blockIdx.x;
    if (b < 5000) {
        int i = b * 256 + threadIdx.x;
        if (i < NC * NN) cnt[i] = 0;
        if (i < NN * 64) hf0[i] = f2h(hv0[i]);
        return;
    }
    if (b >= 5018) {
        // aux regions per t: n<192 & k<64 (12288), n<192 & k in [209,224)
        // (2880), n>=192 all k (14336) -> 29504 per t.
        int aidx = (b - 5018) * 256 + threadIdx.x;
        if (aidx >= 2 * 29504) return;
        int t = aidx / 29504, r = aidx % 29504;
        int n, k;
        if (r < 12288) { n = r >> 6; k = r & 63; }
        else if (r < 15168) { int q = r - 12288; n = q / 15; k = 209 + q % 15; }
        else { int q = r - 15168; n = 192 + q / 224; k = q % 224; }
        float v = 0.f;
        if (n < 192) {
            if (k < 64) {
                if (n < 128) v = W_hh[(size_t)t * 192 * 64 + n * 64 + k];
            } else if (k == 209) {
                v = (n < 128) ? (b_ih[t * 192 + n] + b_hh[t * 192 + n]) : b_ih[t * 192 + n];
            }
        } else {
            int j = n - 64;   // 128..191
            if (k < 64) v = W_hh[(size_t)t * 192 * 64 + j * 64 + k];
            else if (k == 209) v = b_hh[t * 192 + j];
        }
        unsigned short hi, lo;
        splitf(v, hi, lo);
        size_t o = ((size_t)t * 256 + n) * KA + k;
        Bhi[o] = hi;
        Blo[o] = lo;
        return;
    }
    // fold main: WcT[t][j][kw] -> B col map: kw<64 -> 128+kw ; 64..128 -> kw ;
    // 128..144 -> 64+kw (192..207); bacc -> col 208.
    __shared__ float ldsW[64][193];
    int fb = b - 5000;
    int t = fb / 9;
    int k0 = (fb % 9) * 16;
    int j = threadIdx.x;
    float acc[16];
#pragma unroll
    for (int kk = 0; kk < 16; ++kk) acc[kk] = 0.f;
    float bacc = 0.f;
    for (int mc = 0; mc < 2; ++mc) {
        for (int i = threadIdx.x; i < 192 * 64; i += 256) {
            int jj = i >> 6, mm = i & 63;
            ldsW[mm][jj] = W_ih[((size_t)t * 192 + jj) * 128 + mc * 64 + mm];
        }
        __syncthreads();
        if (j < 192) {
            for (int mm = 0; mm < 64; ++mm) {
                float wl = ldsW[mm][j];
                float bm = b_msg[t * 128 + mc * 64 + mm];
                bacc = fmaf(bm, wl, bacc);
#pragma unroll
                for (int kk = 0; kk < 16; ++kk) {
                    float wm = W_msg[((size_t)t * 144 + k0 + kk) * 128 + mc * 64 + mm];
                    acc[kk] = fmaf(wm, wl, acc[kk]);
                }
            }
        }
        __syncthreads();
    }
    if (j < 192) {
        size_t rowo = ((size_t)t * 256 + j) * KA;
#pragma unroll
        for (int kk = 0; kk < 16; ++kk) {
            int kw = k0 + kk;
            int bcol = (kw < 64) ? (128 + kw) : ((kw < 128) ? kw : (64 + kw));
            unsigned short hi, lo;
            splitf(acc[kk], hi, lo);
            Bhi[rowo + bcol] = hi;
            Blo[rowo + bcol] = lo;
        }
        if (k0 == 0) {
            unsigned short hi, lo;
            splitf(bacc, hi, lo);
            Bhi[rowo + 208] = hi;
            Blo[rowo + 208] = lo;
        }
    }
}

__global__ void hist_kernel(const int* __restrict__ dst, int* __restrict__ cnt) {
    int i = blockIdx.x * blockDim.x + threadIdx.x;
    if (i < NE) atomicAdd(&cnt[(i / CHUNK) * NN + dst[i]], 1);
}

__global__ __launch_bounds__(256) void scan1_kernel(const int* __restrict__ cnt,
                                                    int* __restrict__ lp,
                                                    int* __restrict__ bsum) {
    __shared__ int s[256];
    int t = threadIdx.x;
    int i = blockIdx.x * 256 + t;
    int d = 0;
    if (i < NN)
#pragma unroll
        for (int c = 0; c < NC; ++c) d += cnt[c * NN + i];
    s[t] = d;
    __syncthreads();
    for (int off = 1; off < 256; off <<= 1) {
        int v = (t >= off) ? s[t - off] : 0;
        __syncthreads();
        s[t] += v;
        __syncthreads();
    }
    if (i < NN) lp[i] = s[t] - d;
    if (t == 255) bsum[blockIdx.x] = s[255];
}

__global__ __launch_bounds__(256) void scan3_kernel(const int* __restrict__ cnt,
                                                    const int* __restrict__ lp,
                                                    const int* __restrict__ bsum,
                                                    int* __restrict__ row_ptr,
                                                    int* __restrict__ cursor) {
    __shared__ int sb[128];
    int t = threadIdx.x;
    if (t < 128) sb[t] = (t < NB_SCAN) ? bsum[t] : 0;
    __syncthreads();
    for (int off = 1; off < 128; off <<= 1) {
        int u = (t < 128 && t >= off) ? sb[t - off] : 0;
        __syncthreads();
        if (t < 128) sb[t] += u;
        __syncthreads();
    }
    int boff = (blockIdx.x == 0) ? 0 : sb[blockIdx.x - 1];
    int i = blockIdx.x * 256 + t;
    if (i < NN) {
        int run = boff + lp[i];
        row_ptr[i] = run;
#pragma unroll
        for (int c = 0; c < NC; ++c) {
            cursor[c * NN + i] = run;
            run += cnt[c * NN + i];
        }
    }
    if (i == 0) row_ptr[NN] = NE;
}

__global__ void place_kernel(const int* __restrict__ src, const int* __restrict__ dst,
                             int* __restrict__ cursor, int2* __restrict__ adj) {
    int i = blockIdx.x * blockDim.x + threadIdx.x;
    if (i < NE) {
        int d = dst[i];
        int pos = atomicAdd(&cursor[(i / CHUNK) * NN + d], 1);
        adj[pos] = make_int2(src[i], i);
    }
}

// ---------------- per-round ----------------
// A[v][0:224) = [ h | S | deg*h | esum | deg | 1 | 0pad ]; only dgh gets hi/lo.
// FIRST=true also gathers edge features inline (replaces the esum dispatch) and
// writes A's round-invariant tail; FIRST=false skips the tail entirely (Ahi's
// tail persists from round 0).
template <bool FIRST>
__global__ __launch_bounds__(256) void gather_kernel(
        const float* __restrict__ hv, const unsigned short* __restrict__ hf,
        const int* __restrict__ row_ptr, const int2* __restrict__ adj,
        const float* __restrict__ ef,
        unsigned short* __restrict__ Ahi, unsigned short* __restrict__ Alo) {
    int wid = threadIdx.x >> 6, lane = threadIdx.x & 63;
    int v = blockIdx.x * 4 + wid;
    if (v >= NN) return;
    int rp0 = row_ptr[v], rp1 = row_ptr[v + 1];
    int q = lane >> 3;            // 8 edge slots
    int fo = (lane & 7) << 3;     // 8 halfs (16B) per lane
    float a0[8], a1[8], a2[8], a3[8];
#pragma unroll
    for (int j = 0; j < 8; ++j) { a0[j] = 0.f; a1[j] = 0.f; a2[j] = 0.f; a3[j] = 0.f; }
    int i = rp0 + q;
    for (; i + 24 < rp1; i += 32) {
        int s0 = adj[i].x, s1 = adj[i + 8].x, s2 = adj[i + 16].x, s3 = adj[i + 24].x;
        u16x8 x0 = *(const u16x8*)(hf + (size_t)s0 * 64 + fo);
        u16x8 x1 = *(const u16x8*)(hf + (size_t)s1 * 64 + fo);
        u16x8 x2 = *(const u16x8*)(hf + (size_t)s2 * 64 + fo);
        u16x8 x3 = *(const u16x8*)(hf + (size_t)s3 * 64 + fo);
#pragma unroll
        for (int j = 0; j < 8; ++j) {
            a0[j] += h2f(x0[j]); a1[j] += h2f(x1[j]);
            a2[j] += h2f(x2[j]); a3[j] += h2f(x3[j]);
        }
    }
    for (; i < rp1; i += 8) {
        int s = adj[i].x;
        u16x8 x = *(const u16x8*)(hf + (size_t)s * 64 + fo);
#pragma unroll
        for (int j = 0; j < 8; ++j) a0[j] += h2f(x[j]);
    }
#pragma unroll
    for (int j = 0; j < 8; ++j) a0[j] += a1[j] + a2[j] + a3[j];
#pragma unroll
    for (int m = 8; m < 64; m <<= 1)
#pragma unroll
        for (int j = 0; j < 8; ++j) a0[j] += __shfl_xor(a0[j], m);
    float dg = (float)(rp1 - rp0);
    if (lane < 8) {
        float4 hA = *(const float4*)(hv + (size_t)v * 64 + lane * 8);
        float4 hB = *(const float4*)(hv + (size_t)v * 64 + lane * 8 + 4);
        float h8[8] = {hA.x, hA.y, hA.z, hA.w, hB.x, hB.y, hB.z, hB.w};
        u16x8 hh, sh, dh, dl;
#pragma unroll
        for (int j = 0; j < 8; ++j) {
            hh[j] = f2h(h8[j]);
            sh[j] = f2h(a0[j]);
            unsigned short thi, tlo;
            splitf(dg * h8[j], thi, tlo);
            dh[j] = thi; dl[j] = tlo;
        }
        *(u16x8*)(Ahi + (size_t)v * KA + fo) = hh;
        *(u16x8*)(Ahi + (size_t)v * KA + 64 + fo) = sh;
        *(u16x8*)(Ahi + (size_t)v * KA + 128 + fo) = dh;
        *(u16x8*)(Alo + (size_t)v * KA + 128 + fo) = dl;
    }
    if (FIRST) {
        // edge-feature gather (was the esum dispatch): 16 slots x 4 lanes x float4
        int fo2 = (lane & 3) << 2;
        float4 e = make_float4(0.f, 0.f, 0.f, 0.f);
        for (int ii = rp0 + (lane >> 2); ii < rp1; ii += 16) {
            int eid = adj[ii].y;
            float4 x = *(const float4*)(ef + (size_t)eid * 16 + fo2);
            e.x += x.x; e.y += x.y; e.z += x.z; e.w += x.w;
        }
#pragma unroll
        for (int m = 4; m < 64; m <<= 1) {
            e.x += __shfl_xor(e.x, m);
            e.y += __shfl_xor(e.y, m);
            e.z += __shfl_xor(e.z, m);
            e.w += __shfl_xor(e.w, m);
        }
        if (lane < 4) {
            u16x4 tv;
            tv[0] = f2h(e.x); tv[1] = f2h(e.y);
            tv[2] = f2h(e.z); tv[3] = f2h(e.w);
            *(u16x4*)(Ahi + (size_t)v * KA + 192 + lane * 4) = tv;
        } else if (lane == 4) {
            u16x8 tv;
#pragma unroll
            for (int j = 0; j < 8; ++j) tv[j] = 0;
            tv[0] = f2h(dg);
            tv[1] = f2h(1.f);
            *(u16x8*)(Ahi + (size_t)v * KA + 208) = tv;
        } else if (lane == 5) {
            u16x8 tv;
#pragma unroll
            for (int j = 0; j < 8; ++j) tv[j] = 0;
            *(u16x8*)(Ahi + (size_t)v * KA + 216) = tv;
        }
    }
}

// Fused MFMA GEMM (64x256 tile, 256 thr, grid 314) + in-register GRU gates.
// Selective precision (R14, frozen) + zero-block fn skips:
//   phases 0-1 (h):    1 MFMA, fn in {0..7, 12..15}
//   phases 2-3 (S):    1 MFMA, fn in {0..11}
//   phases 4-5 (dgh):  3 MFMA, fn in {0..11}
//   phase  6  (tail):  2 MFMA, fn in {0..15}
__global__ __launch_bounds__(256) void gemm_gru(
        const _Float16* __restrict__ Ahi, const _Float16* __restrict__ Alo,
        const _Float16* __restrict__ Bhi, const _Float16* __restrict__ Blo,
        const float* __restrict__ hin,
        float* __restrict__ fout, unsigned short* __restrict__ hfout) {
    __shared__ _Float16 Ash[64][40];    // +8 pad
    __shared__ _Float16 Asl[64][40];
    __shared__ _Float16 Bsh[256][40];
    __shared__ _Float16 Bsl[256][40];
    int tid = threadIdx.x;
    int w = tid >> 6, l = tid & 63;
    int row0 = blockIdx.x * 64;
    f32x4 acc[16];
#pragma unroll
    for (int i = 0; i < 16; ++i) acc[i] = (f32x4){0.f, 0.f, 0.f, 0.f};

    int sAr = tid >> 2, sAc = (tid & 3) * 8;
    int kg = (l >> 4) * 8;
    int ar = w * 16 + (l & 15);
    int lc = l & 15;

    // ---- phases 0-1: h block — hi only, 1 MFMA, skip fn 8-11 ----
#pragma unroll 1
    for (int ks = 0; ks < 2; ++ks) {
        int k0 = ks * 32;
        *(float4*)&Ash[sAr][sAc] = *(const float4*)(Ahi + (size_t)(row0 + sAr) * KA + k0 + sAc);
        {
            const float4* ph = (const float4*)(Bhi + (size_t)tid * KA + k0);
            float4 h0 = ph[0], h1 = ph[1], h2 = ph[2], h3 = ph[3];
            *(float4*)&Bsh[tid][0] = h0;  *(float4*)&Bsh[tid][8] = h1;
            *(float4*)&Bsh[tid][16] = h2; *(float4*)&Bsh[tid][24] = h3;
        }
        __syncthreads();
        f16x8 ah = *(const f16x8*)&Ash[ar][kg];
#pragma unroll
        for (int fn = 0; fn < 8; ++fn) {
            f16x8 bh = *(const f16x8*)&Bsh[fn * 16 + lc][kg];
            acc[fn] = __builtin_amdgcn_mfma_f32_16x16x32_f16(ah, bh, acc[fn], 0, 0, 0);
        }
#pragma unroll
        for (int fn = 12; fn < 16; ++fn) {
            f16x8 bh = *(const f16x8*)&Bsh[fn * 16 + lc][kg];
            acc[fn] = __builtin_amdgcn_mfma_f32_16x16x32_f16(ah, bh, acc[fn], 0, 0, 0);
        }
        __syncthreads();
    }

    // ---- phases 2-3: S block — hi only, 1 MFMA, fn 0-11 ----
#pragma unroll 1
    for (int ks = 2; ks < 4; ++ks) {
        int k0 = ks * 32;
        *(float4*)&Ash[sAr][sAc] = *(const float4*)(Ahi + (size_t)(row0 + sAr) * KA + k0 + sAc);
        {
            const float4* ph = (const float4*)(Bhi + (size_t)tid * KA + k0);
            float4 h0 = ph[0], h1 = ph[1], h2 = ph[2], h3 = ph[3];
            *(float4*)&Bsh[tid][0] = h0;  *(float4*)&Bsh[tid][8] = h1;
            *(float4*)&Bsh[tid][16] = h2; *(float4*)&Bsh[tid][24] = h3;
        }
        __syncthreads();
        f16x8 ah = *(const f16x8*)&Ash[ar][kg];
#pragma unroll
        for (int fn = 0; fn < 12; ++fn) {
            f16x8 bh = *(const f16x8*)&Bsh[fn * 16 + lc][kg];
            acc[fn] = __builtin_amdgcn_mfma_f32_16x16x32_f16(ah, bh, acc[fn], 0, 0, 0);
        }
        __syncthreads();
    }

    // ---- phases 4-5: dgh block — full hi/lo, 3 MFMA, fn 0-11 ----
#pragma unroll 1
    for (int ks = 4; ks < 6; ++ks) {
        int k0 = ks * 32;
        *(float4*)&Ash[sAr][sAc] = *(const float4*)(Ahi + (size_t)(row0 + sAr) * KA + k0 + sAc);
        *(float4*)&Asl[sAr][sAc] = *(const float4*)(Alo + (size_t)(row0 + sAr) * KA + k0 + sAc);
        {
            const float4* ph = (const float4*)(Bhi + (size_t)tid * KA + k0);
            float4 h0 = ph[0], h1 = ph[1], h2 = ph[2], h3 = ph[3];
            *(float4*)&Bsh[tid][0] = h0;  *(float4*)&Bsh[tid][8] = h1;
            *(float4*)&Bsh[tid][16] = h2; *(float4*)&Bsh[tid][24] = h3;
            const float4* pl = (const float4*)(Blo + (size_t)tid * KA + k0);
            float4 l0 = pl[0], l1 = pl[1], l2 = pl[2], l3 = pl[3];
            *(float4*)&Bsl[tid][0] = l0;  *(float4*)&Bsl[tid][8] = l1;
            *(float4*)&Bsl[tid][16] = l2; *(float4*)&Bsl[tid][24] = l3;
        }
        __syncthreads();
        f16x8 ah = *(const f16x8*)&Ash[ar][kg];
        f16x8 al = *(const f16x8*)&Asl[ar][kg];
#pragma unroll
        for (int fn = 0; fn < 12; ++fn) {
            f16x8 bh = *(const f16x8*)&Bsh[fn * 16 + lc][kg];
            f16x8 bl = *(const f16x8*)&Bsl[fn * 16 + lc][kg];
            acc[fn] = __builtin_amdgcn_mfma_f32_16x16x32_f16(ah, bh, acc[fn], 0, 0, 0);
            acc[fn] = __builtin_amdgcn_mfma_f32_16x16x32_f16(ah, bl, acc[fn], 0, 0, 0);
            acc[fn] = __builtin_amdgcn_mfma_f32_16x16x32_f16(al, bh, acc[fn], 0, 0, 0);
        }
        __syncthreads();
    }

    // ---- phase 6: tail (esum/deg/1/bias) — 2 MFMA, all fn ----
    {
        const int k0 = 192;
        *(float4*)&Ash[sAr][sAc] = *(const float4*)(Ahi + (size_t)(row0 + sAr) * KA + k0 + sAc);
        {
            const float4* ph = (const float4*)(Bhi + (size_t)tid * KA + k0);
            float4 h0 = ph[0], h1 = ph[1], h2 = ph[2], h3 = ph[3];
            *(float4*)&Bsh[tid][0] = h0;  *(float4*)&Bsh[tid][8] = h1;
            *(float4*)&Bsh[tid][16] = h2; *(float4*)&Bsh[tid][24] = h3;
            const float4* pl = (const float4*)(Blo + (size_t)tid * KA + k0);
            float4 l0 = pl[0], l1 = pl[1], l2 = pl[2], l3 = pl[3];
            *(float4*)&Bsl[tid][0] = l0;  *(float4*)&Bsl[tid][8] = l1;
            *(float4*)&Bsl[tid][16] = l2; *(float4*)&Bsl[tid][24] = l3;
        }
        __syncthreads();
        f16x8 ah = *(const f16x8*)&Ash[ar][kg];
#pragma unroll
        for (int fn = 0; fn < 16; ++fn) {
            f16x8 bh = *(const f16x8*)&Bsh[fn * 16 + lc][kg];
            f16x8 bl = *(const f16x8*)&Bsl[fn * 16 + lc][kg];
            acc[fn] = __builtin_amdgcn_mfma_f32_16x16x32_f16(ah, bh, acc[fn], 0, 0, 0);
            acc[fn] = __builtin_amdgcn_mfma_f32_16x16x32_f16(ah, bl, acc[fn], 0, 0, 0);
        }
        __syncthreads();
    }

    // epilogue
    int jb = l & 15;
#pragma unroll
    for (int q = 0; q < 4; ++q) {
        int row = row0 + w * 16 + (l >> 4) * 4 + q;
        if (row >= NN) continue;
#pragma unroll
        for (int fj = 0; fj < 4; ++fj) {
            int j = jb + fj * 16;
            float rr = acc[fj][q];
            float zz = acc[4 + fj][q];
            float in_ = acc[8 + fj][q];
            float hn = acc[12 + fj][q];
            float r = 1.f / (1.f + __expf(-rr));
            float z = 1.f / (1.f + __expf(-zz));
            float n = tanhf(in_ + r * hn);
            float h = hin[(size_t)row * 64 + j];
            float val = (1.f - z) * n + z * h;
            fout[(size_t)row * 64 + j] = val;
            hfout[(size_t)row * 64 + j] = f2h(val);
        }
    }
}

extern "C" void kernel_launch(void* const* d_in, const int* in_sizes, int n_in,
                              void* d_out, int out_size, void* d_ws, size_t ws_size,
                              hipStream_t stream) {
    const float* hv0   = (const float*)d_in[0];
    const float* ef    = (const float*)d_in[1];
    const int*   src   = (const int*)d_in[2];
    const int*   dst   = (const int*)d_in[3];
    const float* W_msg = (const float*)d_in[4];
    const float* b_msg = (const float*)d_in[5];
    const float* W_ih  = (const float*)d_in[6];
    const float* W_hh  = (const float*)d_in[7];
    const float* b_ih  = (const float*)d_in[8];
    const float* b_hh  = (const float*)d_in[9];
    float* out = (float*)d_out;

    char* ws = (char*)d_ws;
    size_t off = 0;
    auto alloc = [&](size_t bytes) -> char* {
        char* p = ws + off;
        off = (off + bytes + 255) & ~(size_t)255;
        return p;
    };
    int*   cnt      = (int*)alloc((size_t)NC * NN * 4);
    int*   row_ptr  = (int*)alloc((NN + 1) * 4);
    int*   cursor   = (int*)alloc((size_t)NC * NN * 4);
    int2*  adj      = (int2*)alloc((size_t)NE * 8);
    int*   lp       = (int*)alloc(NN * 4);
    int*   bsum     = (int*)alloc(NB_SCAN * 4);
    unsigned short* Ahi = (unsigned short*)alloc((size_t)MP * KA * 2);
    unsigned short* Alo = (unsigned short*)alloc((size_t)MP * KA * 2);
    unsigned short* Bhi = (unsigned short*)alloc((size_t)2 * 256 * KA * 2);
    unsigned short* Blo = (unsigned short*)alloc((size_t)2 * 256 * KA * 2);
    float* hv1      = (float*)alloc((size_t)NN * 64 * 4);
    unsigned short* hf0 = (unsigned short*)alloc((size_t)NN * 64 * 2);
    unsigned short* hf1 = (unsigned short*)alloc((size_t)NN * 64 * 2);

    // 5000 init blocks + 18 fold-main + 231 fold-aux
    prep_kernel<<<5000 + 18 + (2 * 29504 + 255) / 256, 256, 0, stream>>>(
        hv0, hf0, cnt, W_msg, b_msg, W_ih, b_ih, b_hh, W_hh, Bhi, Blo);
    hist_kernel<<<(NE + 255) / 256, 256, 0, stream>>>(dst, cnt);
    scan1_kernel<<<NB_SCAN, 256, 0, stream>>>(cnt, lp, bsum);
    scan3_kernel<<<NB_SCAN, 256, 0, stream>>>(cnt, lp, bsum, row_ptr, cursor);
    place_kernel<<<(NE + 255) / 256, 256, 0, stream>>>(src, dst, cursor, adj);

    // round 0 (gather also computes esum inline + writes A tail)
    gather_kernel<true><<<(NN + 3) / 4, 256, 0, stream>>>(
        hv0, hf0, row_ptr, adj, ef, Ahi, Alo);
    gemm_gru<<<MP / 64, 256, 0, stream>>>(
        (const _Float16*)Ahi, (const _Float16*)Alo,
        (const _Float16*)Bhi, (const _Float16*)Blo,
        hv0, hv1, hf1);
    // round 1 (tail persists in Ahi)
    gather_kernel<false><<<(NN + 3) / 4, 256, 0, stream>>>(
        hv1, hf1, row_ptr, adj, ef, Ahi, Alo);
    gemm_gru<<<MP / 64, 256, 0, stream>>>(
        (const _Float16*)Ahi, (const _Float16*)Alo,
        (const _Float16*)(Bhi + (size_t)256 * KA),
        (const _Float16*)(Blo + (size_t)256 * KA),
        hv1, out, hf1);
}

// Round 18
// 181.074 us; speedup vs baseline: 1.0993x; 1.0060x over previous
//
#include <hip/hip_runtime.h>
#include <cstddef>
#include <cstdint>

#define NN 20000
#define NE 640000
#define MP 20096       // padded rows (314*64)
#define KA 224         // A row length (halfs)
#define NC 16
#define CHUNK 40000    // NE / NC
#define NB_SCAN 79     // ceil(NN/256)

typedef _Float16 f16x8 __attribute__((ext_vector_type(8)));
typedef float f32x4 __attribute__((ext_vector_type(4)));
typedef unsigned short u16x8 __attribute__((ext_vector_type(8)));
typedef unsigned short u16x4 __attribute__((ext_vector_type(4)));

__device__ __forceinline__ float h2f(unsigned short u) {
    _Float16 h;
    *reinterpret_cast<unsigned short*>(&h) = u;
    return (float)h;
}
__device__ __forceinline__ unsigned short f2h(float f) {
    _Float16 h = (_Float16)f;
    return *reinterpret_cast<unsigned short*>(&h);
}
// fp16 two-term split: x ~= hi + lo (22 effective mantissa bits)
__device__ __forceinline__ void splitf(float x, unsigned short& hi, unsigned short& lo) {
    _Float16 h = (_Float16)x;
    _Float16 l = (_Float16)(x - (float)h);
    hi = *reinterpret_cast<unsigned short*>(&h);
    lo = *reinterpret_cast<unsigned short*>(&l);
}

// ---------------- setup ----------------
// ONE prep kernel:
//   blocks [0,5000):     zero cnt (+gcounter) + build fp16 h table
//   blocks [5000,5018):  fold main (t, k0-chunk) -> B direct (mapped cols)
//   blocks [5018,5249):  fold aux  (W_hh regions, bias col 209, zeros)
__global__ __launch_bounds__(256) void prep_kernel(
        const float* __restrict__ hv0, unsigned short* __restrict__ hf0,
        int* __restrict__ cnt, int* __restrict__ gcounter,
        const float* __restrict__ W_msg, const float* __restrict__ b_msg,
        const float* __restrict__ W_ih, const float* __restrict__ b_ih,
        const float* __restrict__ b_hh, const float* __restrict__ W_hh,
        unsigned short* __restrict__ Bhi, unsigned short* __restrict__ Blo) {
    int b = blockIdx.x;
    if (b < 5000) {
        int i = b * 256 + threadIdx.x;
        if (i == 0) *gcounter = 0;
        if (i < NC * NN) cnt[i] = 0;
        if (i < NN * 64) hf0[i] = f2h(hv0[i]);
        return;
    }
    if (b >= 5018) {
        // aux regions per t: n<192 & k<64 (12288), n<192 & k in [209,224)
        // (2880), n>=192 all k (14336) -> 29504 per t.
        int aidx = (b - 5018) * 256 + threadIdx.x;
        if (aidx >= 2 * 29504) return;
        int t = aidx / 29504, r = aidx % 29504;
        int n, k;
        if (r < 12288) { n = r >> 6; k = r & 63; }
        else if (r < 15168) { int q = r - 12288; n = q / 15; k = 209 + q % 15; }
        else { int q = r - 15168; n = 192 + q / 224; k = q % 224; }
        float v = 0.f;
        if (n < 192) {
            if (k < 64) {
                if (n < 128) v = W_hh[(size_t)t * 192 * 64 + n * 64 + k];
            } else if (k == 209) {
                v = (n < 128) ? (b_ih[t * 192 + n] + b_hh[t * 192 + n]) : b_ih[t * 192 + n];
            }
        } else {
            int j = n - 64;   // 128..191
            if (k < 64) v = W_hh[(size_t)t * 192 * 64 + j * 64 + k];
            else if (k == 209) v = b_hh[t * 192 + j];
        }
        unsigned short hi, lo;
        splitf(v, hi, lo);
        size_t o = ((size_t)t * 256 + n) * KA + k;
        Bhi[o] = hi;
        Blo[o] = lo;
        return;
    }
    // fold main: WcT[t][j][kw] -> B col map: kw<64 -> 128+kw ; 64..128 -> kw ;
    // 128..144 -> 64+kw (192..207); bacc -> col 208.
    __shared__ float ldsW[64][193];
    int fb = b - 5000;
    int t = fb / 9;
    int k0 = (fb % 9) * 16;
    int j = threadIdx.x;
    float acc[16];
#pragma unroll
    for (int kk = 0; kk < 16; ++kk) acc[kk] = 0.f;
    float bacc = 0.f;
    for (int mc = 0; mc < 2; ++mc) {
        for (int i = threadIdx.x; i < 192 * 64; i += 256) {
            int jj = i >> 6, mm = i & 63;
            ldsW[mm][jj] = W_ih[((size_t)t * 192 + jj) * 128 + mc * 64 + mm];
        }
        __syncthreads();
        if (j < 192) {
            for (int mm = 0; mm < 64; ++mm) {
                float wl = ldsW[mm][j];
                float bm = b_msg[t * 128 + mc * 64 + mm];
                bacc = fmaf(bm, wl, bacc);
#pragma unroll
                for (int kk = 0; kk < 16; ++kk) {
                    float wm = W_msg[((size_t)t * 144 + k0 + kk) * 128 + mc * 64 + mm];
                    acc[kk] = fmaf(wm, wl, acc[kk]);
                }
            }
        }
        __syncthreads();
    }
    if (j < 192) {
        size_t rowo = ((size_t)t * 256 + j) * KA;
#pragma unroll
        for (int kk = 0; kk < 16; ++kk) {
            int kw = k0 + kk;
            int bcol = (kw < 64) ? (128 + kw) : ((kw < 128) ? kw : (64 + kw));
            unsigned short hi, lo;
            splitf(acc[kk], hi, lo);
            Bhi[rowo + bcol] = hi;
            Blo[rowo + bcol] = lo;
        }
        if (k0 == 0) {
            unsigned short hi, lo;
            splitf(bacc, hi, lo);
            Bhi[rowo + 208] = hi;
            Blo[rowo + 208] = lo;
        }
    }
}

__global__ void hist_kernel(const int* __restrict__ dst, int* __restrict__ cnt) {
    int i = blockIdx.x * blockDim.x + threadIdx.x;
    if (i < NE) atomicAdd(&cnt[(i / CHUNK) * NN + dst[i]], 1);
}

// Single-dispatch scan (R17 post-mortem: chain-shortening pays ~5-7 µs/link).
// Per-block local LDS scan + ONE atomicAdd for the block base — regions land
// in arbitrary block order, which nothing downstream depends on (gather uses
// row_ptr[v] + deg[v]; within-node edge ordering unchanged -> sums identical).
__global__ __launch_bounds__(256) void scan_kernel(const int* __restrict__ cnt,
                                                   int* __restrict__ gcounter,
                                                   int* __restrict__ row_ptr,
                                                   int* __restrict__ deg,
                                                   int* __restrict__ cursor) {
    __shared__ int s[256];
    __shared__ int base_sh;
    int t = threadIdx.x;
    int i = blockIdx.x * 256 + t;
    int d = 0;
    if (i < NN)
#pragma unroll
        for (int c = 0; c < NC; ++c) d += cnt[c * NN + i];
    s[t] = d;
    __syncthreads();
    for (int off = 1; off < 256; off <<= 1) {
        int v = (t >= off) ? s[t - off] : 0;
        __syncthreads();
        s[t] += v;
        __syncthreads();
    }
    if (t == 255) base_sh = atomicAdd(gcounter, s[255]);
    __syncthreads();
    if (i < NN) {
        int run = base_sh + s[t] - d;
        row_ptr[i] = run;
        deg[i] = d;
#pragma unroll
        for (int c = 0; c < NC; ++c) {
            cursor[c * NN + i] = run;
            run += cnt[c * NN + i];
        }
    }
}

__global__ void place_kernel(const int* __restrict__ src, const int* __restrict__ dst,
                             int* __restrict__ cursor, int2* __restrict__ adj) {
    int i = blockIdx.x * blockDim.x + threadIdx.x;
    if (i < NE) {
        int d = dst[i];
        int pos = atomicAdd(&cursor[(i / CHUNK) * NN + d], 1);
        adj[pos] = make_int2(src[i], i);
    }
}

// ---------------- per-round ----------------
// A[v][0:224) = [ h | S | deg*h | esum | deg | 1 | 0pad ]; only dgh gets hi/lo.
// FIRST=true also gathers edge features inline and writes A's round-invariant
// tail; FIRST=false skips the tail (persists in Ahi from round 0).
template <bool FIRST>
__global__ __launch_bounds__(256) void gather_kernel(
        const float* __restrict__ hv, const unsigned short* __restrict__ hf,
        const int* __restrict__ row_ptr, const int* __restrict__ degp,
        const int2* __restrict__ adj, const float* __restrict__ ef,
        unsigned short* __restrict__ Ahi, unsigned short* __restrict__ Alo) {
    int wid = threadIdx.x >> 6, lane = threadIdx.x & 63;
    int v = blockIdx.x * 4 + wid;
    if (v >= NN) return;
    int rp0 = row_ptr[v];
    int dgi = degp[v];
    int rp1 = rp0 + dgi;
    int q = lane >> 3;            // 8 edge slots
    int fo = (lane & 7) << 3;     // 8 halfs (16B) per lane
    float a0[8], a1[8], a2[8], a3[8];
#pragma unroll
    for (int j = 0; j < 8; ++j) { a0[j] = 0.f; a1[j] = 0.f; a2[j] = 0.f; a3[j] = 0.f; }
    int i = rp0 + q;
    for (; i + 24 < rp1; i += 32) {
        int s0 = adj[i].x, s1 = adj[i + 8].x, s2 = adj[i + 16].x, s3 = adj[i + 24].x;
        u16x8 x0 = *(const u16x8*)(hf + (size_t)s0 * 64 + fo);
        u16x8 x1 = *(const u16x8*)(hf + (size_t)s1 * 64 + fo);
        u16x8 x2 = *(const u16x8*)(hf + (size_t)s2 * 64 + fo);
        u16x8 x3 = *(const u16x8*)(hf + (size_t)s3 * 64 + fo);
#pragma unroll
        for (int j = 0; j < 8; ++j) {
            a0[j] += h2f(x0[j]); a1[j] += h2f(x1[j]);
            a2[j] += h2f(x2[j]); a3[j] += h2f(x3[j]);
        }
    }
    for (; i < rp1; i += 8) {
        int s = adj[i].x;
        u16x8 x = *(const u16x8*)(hf + (size_t)s * 64 + fo);
#pragma unroll
        for (int j = 0; j < 8; ++j) a0[j] += h2f(x[j]);
    }
#pragma unroll
    for (int j = 0; j < 8; ++j) a0[j] += a1[j] + a2[j] + a3[j];
#pragma unroll
    for (int m = 8; m < 64; m <<= 1)
#pragma unroll
        for (int j = 0; j < 8; ++j) a0[j] += __shfl_xor(a0[j], m);
    float dg = (float)dgi;
    if (lane < 8) {
        float4 hA = *(const float4*)(hv + (size_t)v * 64 + lane * 8);
        float4 hB = *(const float4*)(hv + (size_t)v * 64 + lane * 8 + 4);
        float h8[8] = {hA.x, hA.y, hA.z, hA.w, hB.x, hB.y, hB.z, hB.w};
        u16x8 hh, sh, dh, dl;
#pragma unroll
        for (int j = 0; j < 8; ++j) {
            hh[j] = f2h(h8[j]);
            sh[j] = f2h(a0[j]);
            unsigned short thi, tlo;
            splitf(dg * h8[j], thi, tlo);
            dh[j] = thi; dl[j] = tlo;
        }
        *(u16x8*)(Ahi + (size_t)v * KA + fo) = hh;
        *(u16x8*)(Ahi + (size_t)v * KA + 64 + fo) = sh;
        *(u16x8*)(Ahi + (size_t)v * KA + 128 + fo) = dh;
        *(u16x8*)(Alo + (size_t)v * KA + 128 + fo) = dl;
    }
    if (FIRST) {
        // edge-feature gather: 16 slots x 4 lanes x float4
        int fo2 = (lane & 3) << 2;
        float4 e = make_float4(0.f, 0.f, 0.f, 0.f);
        for (int ii = rp0 + (lane >> 2); ii < rp1; ii += 16) {
            int eid = adj[ii].y;
            float4 x = *(const float4*)(ef + (size_t)eid * 16 + fo2);
            e.x += x.x; e.y += x.y; e.z += x.z; e.w += x.w;
        }
#pragma unroll
        for (int m = 4; m < 64; m <<= 1) {
            e.x += __shfl_xor(e.x, m);
            e.y += __shfl_xor(e.y, m);
            e.z += __shfl_xor(e.z, m);
            e.w += __shfl_xor(e.w, m);
        }
        if (lane < 4) {
            u16x4 tv;
            tv[0] = f2h(e.x); tv[1] = f2h(e.y);
            tv[2] = f2h(e.z); tv[3] = f2h(e.w);
            *(u16x4*)(Ahi + (size_t)v * KA + 192 + lane * 4) = tv;
        } else if (lane == 4) {
            u16x8 tv;
#pragma unroll
            for (int j = 0; j < 8; ++j) tv[j] = 0;
            tv[0] = f2h(dg);
            tv[1] = f2h(1.f);
            *(u16x8*)(Ahi + (size_t)v * KA + 208) = tv;
        } else if (lane == 5) {
            u16x8 tv;
#pragma unroll
            for (int j = 0; j < 8; ++j) tv[j] = 0;
            *(u16x8*)(Ahi + (size_t)v * KA + 216) = tv;
        }
    }
}

// Fused MFMA GEMM (64x256 tile, 256 thr, grid 314) + in-register GRU gates.
// Selective precision (R14, frozen) + zero-block fn skips:
//   phases 0-1 (h):    1 MFMA, fn in {0..7, 12..15}
//   phases 2-3 (S):    1 MFMA, fn in {0..11}
//   phases 4-5 (dgh):  3 MFMA, fn in {0..11}
//   phase  6  (tail):  2 MFMA, fn in {0..15}
__global__ __launch_bounds__(256) void gemm_gru(
        const _Float16* __restrict__ Ahi, const _Float16* __restrict__ Alo,
        const _Float16* __restrict__ Bhi, const _Float16* __restrict__ Blo,
        const float* __restrict__ hin,
        float* __restrict__ fout, unsigned short* __restrict__ hfout) {
    __shared__ _Float16 Ash[64][40];    // +8 pad
    __shared__ _Float16 Asl[64][40];
    __shared__ _Float16 Bsh[256][40];
    __shared__ _Float16 Bsl[256][40];
    int tid = threadIdx.x;
    int w = tid >> 6, l = tid & 63;
    int row0 = blockIdx.x * 64;
    f32x4 acc[16];
#pragma unroll
    for (int i = 0; i < 16; ++i) acc[i] = (f32x4){0.f, 0.f, 0.f, 0.f};

    int sAr = tid >> 2, sAc = (tid & 3) * 8;
    int kg = (l >> 4) * 8;
    int ar = w * 16 + (l & 15);
    int lc = l & 15;

    // ---- phases 0-1: h block — hi only, 1 MFMA, skip fn 8-11 ----
#pragma unroll 1
    for (int ks = 0; ks < 2; ++ks) {
        int k0 = ks * 32;
        *(float4*)&Ash[sAr][sAc] = *(const float4*)(Ahi + (size_t)(row0 + sAr) * KA + k0 + sAc);
        {
            const float4* ph = (const float4*)(Bhi + (size_t)tid * KA + k0);
            float4 h0 = ph[0], h1 = ph[1], h2 = ph[2], h3 = ph[3];
            *(float4*)&Bsh[tid][0] = h0;  *(float4*)&Bsh[tid][8] = h1;
            *(float4*)&Bsh[tid][16] = h2; *(float4*)&Bsh[tid][24] = h3;
        }
        __syncthreads();
        f16x8 ah = *(const f16x8*)&Ash[ar][kg];
#pragma unroll
        for (int fn = 0; fn < 8; ++fn) {
            f16x8 bh = *(const f16x8*)&Bsh[fn * 16 + lc][kg];
            acc[fn] = __builtin_amdgcn_mfma_f32_16x16x32_f16(ah, bh, acc[fn], 0, 0, 0);
        }
#pragma unroll
        for (int fn = 12; fn < 16; ++fn) {
            f16x8 bh = *(const f16x8*)&Bsh[fn * 16 + lc][kg];
            acc[fn] = __builtin_amdgcn_mfma_f32_16x16x32_f16(ah, bh, acc[fn], 0, 0, 0);
        }
        __syncthreads();
    }

    // ---- phases 2-3: S block — hi only, 1 MFMA, fn 0-11 ----
#pragma unroll 1
    for (int ks = 2; ks < 4; ++ks) {
        int k0 = ks * 32;
        *(float4*)&Ash[sAr][sAc] = *(const float4*)(Ahi + (size_t)(row0 + sAr) * KA + k0 + sAc);
        {
            const float4* ph = (const float4*)(Bhi + (size_t)tid * KA + k0);
            float4 h0 = ph[0], h1 = ph[1], h2 = ph[2], h3 = ph[3];
            *(float4*)&Bsh[tid][0] = h0;  *(float4*)&Bsh[tid][8] = h1;
            *(float4*)&Bsh[tid][16] = h2; *(float4*)&Bsh[tid][24] = h3;
        }
        __syncthreads();
        f16x8 ah = *(const f16x8*)&Ash[ar][kg];
#pragma unroll
        for (int fn = 0; fn < 12; ++fn) {
            f16x8 bh = *(const f16x8*)&Bsh[fn * 16 + lc][kg];
            acc[fn] = __builtin_amdgcn_mfma_f32_16x16x32_f16(ah, bh, acc[fn], 0, 0, 0);
        }
        __syncthreads();
    }

    // ---- phases 4-5: dgh block — full hi/lo, 3 MFMA, fn 0-11 ----
#pragma unroll 1
    for (int ks = 4; ks < 6; ++ks) {
        int k0 = ks * 32;
        *(float4*)&Ash[sAr][sAc] = *(const float4*)(Ahi + (size_t)(row0 + sAr) * KA + k0 + sAc);
        *(float4*)&Asl[sAr][sAc] = *(const float4*)(Alo + (size_t)(row0 + sAr) * KA + k0 + sAc);
        {
            const float4* ph = (const float4*)(Bhi + (size_t)tid * KA + k0);
            float4 h0 = ph[0], h1 = ph[1], h2 = ph[2], h3 = ph[3];
            *(float4*)&Bsh[tid][0] = h0;  *(float4*)&Bsh[tid][8] = h1;
            *(float4*)&Bsh[tid][16] = h2; *(float4*)&Bsh[tid][24] = h3;
            const float4* pl = (const float4*)(Blo + (size_t)tid * KA + k0);
            float4 l0 = pl[0], l1 = pl[1], l2 = pl[2], l3 = pl[3];
            *(float4*)&Bsl[tid][0] = l0;  *(float4*)&Bsl[tid][8] = l1;
            *(float4*)&Bsl[tid][16] = l2; *(float4*)&Bsl[tid][24] = l3;
        }
        __syncthreads();
        f16x8 ah = *(const f16x8*)&Ash[ar][kg];
        f16x8 al = *(const f16x8*)&Asl[ar][kg];
#pragma unroll
        for (int fn = 0; fn < 12; ++fn) {
            f16x8 bh = *(const f16x8*)&Bsh[fn * 16 + lc][kg];
            f16x8 bl = *(const f16x8*)&Bsl[fn * 16 + lc][kg];
            acc[fn] = __builtin_amdgcn_mfma_f32_16x16x32_f16(ah, bh, acc[fn], 0, 0, 0);
            acc[fn] = __builtin_amdgcn_mfma_f32_16x16x32_f16(ah, bl, acc[fn], 0, 0, 0);
            acc[fn] = __builtin_amdgcn_mfma_f32_16x16x32_f16(al, bh, acc[fn], 0, 0, 0);
        }
        __syncthreads();
    }

    // ---- phase 6: tail (esum/deg/1/bias) — 2 MFMA, all fn ----
    {
        const int k0 = 192;
        *(float4*)&Ash[sAr][sAc] = *(const float4*)(Ahi + (size_t)(row0 + sAr) * KA + k0 + sAc);
        {
            const float4* ph = (const float4*)(Bhi + (size_t)tid * KA + k0);
            float4 h0 = ph[0], h1 = ph[1], h2 = ph[2], h3 = ph[3];
            *(float4*)&Bsh[tid][0] = h0;  *(float4*)&Bsh[tid][8] = h1;
            *(float4*)&Bsh[tid][16] = h2; *(float4*)&Bsh[tid][24] = h3;
            const float4* pl = (const float4*)(Blo + (size_t)tid * KA + k0);
            float4 l0 = pl[0], l1 = pl[1], l2 = pl[2], l3 = pl[3];
            *(float4*)&Bsl[tid][0] = l0;  *(float4*)&Bsl[tid][8] = l1;
            *(float4*)&Bsl[tid][16] = l2; *(float4*)&Bsl[tid][24] = l3;
        }
        __syncthreads();
        f16x8 ah = *(const f16x8*)&Ash[ar][kg];
#pragma unroll
        for (int fn = 0; fn < 16; ++fn) {
            f16x8 bh = *(const f16x8*)&Bsh[fn * 16 + lc][kg];
            f16x8 bl = *(const f16x8*)&Bsl[fn * 16 + lc][kg];
            acc[fn] = __builtin_amdgcn_mfma_f32_16x16x32_f16(ah, bh, acc[fn], 0, 0, 0);
            acc[fn] = __builtin_amdgcn_mfma_f32_16x16x32_f16(ah, bl, acc[fn], 0, 0, 0);
        }
        __syncthreads();
    }

    // epilogue
    int jb = l & 15;
#pragma unroll
    for (int q = 0; q < 4; ++q) {
        int row = row0 + w * 16 + (l >> 4) * 4 + q;
        if (row >= NN) continue;
#pragma unroll
        for (int fj = 0; fj < 4; ++fj) {
            int j = jb + fj * 16;
            float rr = acc[fj][q];
            float zz = acc[4 + fj][q];
            float in_ = acc[8 + fj][q];
            float hn = acc[12 + fj][q];
            float r = 1.f / (1.f + __expf(-rr));
            float z = 1.f / (1.f + __expf(-zz));
            float n = tanhf(in_ + r * hn);
            float h = hin[(size_t)row * 64 + j];
            float val = (1.f - z) * n + z * h;
            fout[(size_t)row * 64 + j] = val;
            hfout[(size_t)row * 64 + j] = f2h(val);
        }
    }
}

extern "C" void kernel_launch(void* const* d_in, const int* in_sizes, int n_in,
                              void* d_out, int out_size, void* d_ws, size_t ws_size,
                              hipStream_t stream) {
    const float* hv0   = (const float*)d_in[0];
    const float* ef    = (const float*)d_in[1];
    const int*   src   = (const int*)d_in[2];
    const int*   dst   = (const int*)d_in[3];
    const float* W_msg = (const float*)d_in[4];
    const float* b_msg = (const float*)d_in[5];
    const float* W_ih  = (const float*)d_in[6];
    const float* W_hh  = (const float*)d_in[7];
    const float* b_ih  = (const float*)d_in[8];
    const float* b_hh  = (const float*)d_in[9];
    float* out = (float*)d_out;

    char* ws = (char*)d_ws;
    size_t off = 0;
    auto alloc = [&](size_t bytes) -> char* {
        char* p = ws + off;
        off = (off + bytes + 255) & ~(size_t)255;
        return p;
    };
    int*   cnt      = (int*)alloc((size_t)NC * NN * 4);
    int*   row_ptr  = (int*)alloc(NN * 4);
    int*   deg      = (int*)alloc(NN * 4);
    int*   cursor   = (int*)alloc((size_t)NC * NN * 4);
    int*   gcounter = (int*)alloc(4);
    int2*  adj      = (int2*)alloc((size_t)NE * 8);
    unsigned short* Ahi = (unsigned short*)alloc((size_t)MP * KA * 2);
    unsigned short* Alo = (unsigned short*)alloc((size_t)MP * KA * 2);
    unsigned short* Bhi = (unsigned short*)alloc((size_t)2 * 256 * KA * 2);
    unsigned short* Blo = (unsigned short*)alloc((size_t)2 * 256 * KA * 2);
    float* hv1      = (float*)alloc((size_t)NN * 64 * 4);
    unsigned short* hf0 = (unsigned short*)alloc((size_t)NN * 64 * 2);
    unsigned short* hf1 = (unsigned short*)alloc((size_t)NN * 64 * 2);

    // 5000 init blocks + 18 fold-main + 231 fold-aux
    prep_kernel<<<5000 + 18 + (2 * 29504 + 255) / 256, 256, 0, stream>>>(
        hv0, hf0, cnt, gcounter, W_msg, b_msg, W_ih, b_ih, b_hh, W_hh, Bhi, Blo);
    hist_kernel<<<(NE + 255) / 256, 256, 0, stream>>>(dst, cnt);
    scan_kernel<<<NB_SCAN, 256, 0, stream>>>(cnt, gcounter, row_ptr, deg, cursor);
    place_kernel<<<(NE + 255) / 256, 256, 0, stream>>>(src, dst, cursor, adj);

    // round 0 (gather also computes esum inline + writes A tail)
    gather_kernel<true><<<(NN + 3) / 4, 256, 0, stream>>>(
        hv0, hf0, row_ptr, deg, adj, ef, Ahi, Alo);
    gemm_gru<<<MP / 64, 256, 0, stream>>>(
        (const _Float16*)Ahi, (const _Float16*)Alo,
        (const _Float16*)Bhi, (const _Float16*)Blo,
        hv0, hv1, hf1);
    // round 1 (tail persists in Ahi)
    gather_kernel<false><<<(NN + 3) / 4, 256, 0, stream>>>(
        hv1, hf1, row_ptr, deg, adj, ef, Ahi, Alo);
    gemm_gru<<<MP / 64, 256, 0, stream>>>(
        (const _Float16*)Ahi, (const _Float16*)Alo,
        (const _Float16*)(Bhi + (size_t)256 * KA),
        (const _Float16*)(Blo + (size_t)256 * KA),
        hv1, out, hf1);
}